// Round 6
// baseline (595.937 us; speedup 1.0000x reference)
//
#include <hip/hip_runtime.h>
#include <hip/hip_bf16.h>
#include <math.h>

#define NN 100000
#define NE 1600000
#define HID 128
#define NG 512
#define NB 512          // dst buckets
#define RB 196          // nodes per bucket (512*196 = 100352 >= NN)

typedef unsigned short ushort_t;
typedef __attribute__((ext_vector_type(8))) short bf16x8;
typedef __attribute__((ext_vector_type(8))) unsigned short ushort8_t;
typedef __attribute__((ext_vector_type(4))) float f32x4;

__device__ __forceinline__ ushort_t f2bf(float v) {
    unsigned u = __float_as_uint(v);
    unsigned r = (u + 0x7FFF + ((u >> 16) & 1)) >> 16;
    return (ushort_t)r;
}
__device__ __forceinline__ float bf2f(ushort_t u) {
    return __uint_as_float((unsigned)u << 16);
}

// ---------------- bucket histogram ----------------
__global__ __launch_bounds__(256) void bucket_hist(const int* __restrict__ ecol, int* __restrict__ ghist, int E) {
    __shared__ int lh[NB];
    for (int i = threadIdx.x; i < NB; i += 256) lh[i] = 0;
    __syncthreads();
    for (int e = blockIdx.x * 256 + threadIdx.x; e < E; e += gridDim.x * 256)
        atomicAdd(&lh[ecol[e] / RB], 1);
    __syncthreads();
    for (int i = threadIdx.x; i < NB; i += 256) {
        int c = lh[i];
        if (c) atomicAdd(&ghist[i], c);
    }
}

// ---------------- scan buckets ----------------
__global__ __launch_bounds__(NB) void bucket_scan(const int* __restrict__ ghist, int* __restrict__ brp,
                                                  int* __restrict__ gcur, int* __restrict__ rp) {
    __shared__ int s[NB];
    int t = threadIdx.x;
    int v = ghist[t];
    s[t] = v;
    __syncthreads();
    for (int off = 1; off < NB; off <<= 1) {
        int x = (t >= off) ? s[t - off] : 0;
        __syncthreads();
        s[t] += x;
        __syncthreads();
    }
    int ex = s[t] - v;
    brp[t] = ex;
    gcur[t] = ex;
    if (t == NB - 1) { brp[NB] = s[t]; rp[NN] = s[t]; }
}

// ---------------- partition edges into bucket-contiguous (src,dst) pairs ----------------
#define CHUNK 4096
__global__ __launch_bounds__(256) void partition_edges(const int* __restrict__ erow, const int* __restrict__ ecol,
                                                       int* __restrict__ gcur, int2* __restrict__ pairs, int E) {
    __shared__ int cnt[NB];
    __shared__ int base[NB];
    const int t = threadIdx.x;
    const int e0 = blockIdx.x * CHUNK;
    const int e1 = min(e0 + CHUNK, E);
    for (int i = t; i < NB; i += 256) cnt[i] = 0;
    __syncthreads();
    for (int e = e0 + t; e < e1; e += 256) atomicAdd(&cnt[ecol[e] / RB], 1);
    __syncthreads();
    for (int i = t; i < NB; i += 256) {
        int c = cnt[i];
        base[i] = c ? atomicAdd(&gcur[i], c) : 0;
        cnt[i] = 0;
    }
    __syncthreads();
    for (int e = e0 + t; e < e1; e += 256) {
        int d = ecol[e];
        int b = d / RB;
        int off = atomicAdd(&cnt[b], 1);
        pairs[base[b] + off] = make_int2(erow[e], d);
    }
}

// ---------------- per-bucket: degrees, dinv, rp, fill csrc ----------------
__global__ __launch_bounds__(256) void bucket_fill(const int2* __restrict__ pairs, const int* __restrict__ brp,
                                                   int* __restrict__ rp, float* __restrict__ dinv,
                                                   int* __restrict__ csrc) {
    __shared__ int cnt[RB];
    __shared__ int cur[RB];
    __shared__ int sc[256];
    const int b = blockIdx.x, t = threadIdx.x;
    const int nbase = b * RB;
    const int s = brp[b], e = brp[b + 1];
    for (int i = t; i < RB; i += 256) cnt[i] = 0;
    __syncthreads();
    for (int i = s + t; i < e; i += 256) atomicAdd(&cnt[pairs[i].y - nbase], 1);
    __syncthreads();
    int v = (t < RB) ? cnt[t] : 0;
    sc[t] = v;
    __syncthreads();
    for (int off = 1; off < 256; off <<= 1) {
        int x = (t >= off) ? sc[t - off] : 0;
        __syncthreads();
        sc[t] += x;
        __syncthreads();
    }
    if (t < RB) {
        int ex = s + sc[t] - v;
        int node = nbase + t;
        if (node < NN) {
            rp[node] = ex;
            dinv[node] = rsqrtf((float)v + 1.0f);
        }
        cur[t] = ex;
    }
    __syncthreads();
    for (int i = s + t; i < e; i += 256) {
        int2 p = pairs[i];
        int slot = atomicAdd(&cur[p.y - nbase], 1);
        csrc[slot] = p.x;
    }
}

// ---------------- weight prep: transpose + bf16 hi/lo split ----------------
__global__ __launch_bounds__(256) void prep_w(const float* __restrict__ lin1_w,
                                              const float* __restrict__ gcn_w,
                                              ushort_t* __restrict__ wt_hi,
                                              ushort_t* __restrict__ wt_lo) {
    int m = blockIdx.x >> 3;
    int chunk = blockIdx.x & 7;
    const float* W = (m == 0) ? lin1_w : gcn_w + (size_t)(m - 1) * 16384;
    ushort_t* hi = wt_hi + (size_t)m * 16384;
    ushort_t* lo = wt_lo + (size_t)m * 16384;
    for (int i = chunk * 2048 + threadIdx.x; i < (chunk + 1) * 2048; i += 256) {
        int k = i >> 7, n = i & 127;
        float v = W[i];
        ushort_t h = f2bf(v);
        ushort_t l = f2bf(v - bf2f(h));
        hi[n * 128 + k] = h;
        lo[n * 128 + k] = l;
    }
}

// ---------------- MFMA GEMM, 3-term bf16 split ----------------
// F32A: A from fp32 (convert in-kernel); else A from pre-split a_hi/a_lo.
// MODE 0: h_hi/h_lo = split(elu(acc + bias)); MODE 1: hwb = bf16(dinv[row]*acc)
template<bool F32A, int MODE>
__global__ __launch_bounds__(256) void gemm_mfma(const float* __restrict__ A,
                                                 const ushort_t* __restrict__ a_hi,
                                                 const ushort_t* __restrict__ a_lo,
                                                 const ushort_t* __restrict__ wt_hi,
                                                 const ushort_t* __restrict__ wt_lo,
                                                 const float* __restrict__ bias,
                                                 const float* __restrict__ dinv,
                                                 ushort_t* __restrict__ out0,
                                                 ushort_t* __restrict__ out1,
                                                 int N) {
    const int lane = threadIdx.x & 63;
    const int wid = threadIdx.x >> 6;
    const int rowBase = blockIdx.x * 128 + wid * 32;
    const int l15 = lane & 15, lg = lane >> 4;

    f32x4 acc[2][8];
#pragma unroll
    for (int rt = 0; rt < 2; ++rt)
#pragma unroll
        for (int ct = 0; ct < 8; ++ct) acc[rt][ct] = (f32x4){0.f, 0.f, 0.f, 0.f};

#pragma unroll
    for (int ks = 0; ks < 4; ++ks) {
        bf16x8 ahi[2], alo[2];
#pragma unroll
        for (int rt = 0; rt < 2; ++rt) {
            int r = rowBase + rt * 16 + l15;
            if (F32A) {
                float av[8];
                if (r < N) {
                    const float* ap = A + (size_t)r * 128 + ks * 32 + lg * 8;
                    float4 a0 = *(const float4*)(ap);
                    float4 a1 = *(const float4*)(ap + 4);
                    av[0] = a0.x; av[1] = a0.y; av[2] = a0.z; av[3] = a0.w;
                    av[4] = a1.x; av[5] = a1.y; av[6] = a1.z; av[7] = a1.w;
                } else {
#pragma unroll
                    for (int j = 0; j < 8; ++j) av[j] = 0.f;
                }
#pragma unroll
                for (int j = 0; j < 8; ++j) {
                    ushort_t h = f2bf(av[j]);
                    ahi[rt][j] = (short)h;
                    alo[rt][j] = (short)f2bf(av[j] - bf2f(h));
                }
            } else {
                if (r < N) {
                    size_t off = (size_t)r * 128 + ks * 32 + lg * 8;
                    ahi[rt] = *(const bf16x8*)(a_hi + off);
                    alo[rt] = *(const bf16x8*)(a_lo + off);
                } else {
                    bf16x8 z = {0, 0, 0, 0, 0, 0, 0, 0};
                    ahi[rt] = z;
                    alo[rt] = z;
                }
            }
        }
#pragma unroll
        for (int ct = 0; ct < 8; ++ct) {
            size_t boff = (size_t)(ct * 16 + l15) * 128 + ks * 32 + lg * 8;
            bf16x8 bhi = *(const bf16x8*)(wt_hi + boff);
            bf16x8 blo = *(const bf16x8*)(wt_lo + boff);
            acc[0][ct] = __builtin_amdgcn_mfma_f32_16x16x32_bf16(ahi[0], bhi, acc[0][ct], 0, 0, 0);
            acc[1][ct] = __builtin_amdgcn_mfma_f32_16x16x32_bf16(ahi[1], bhi, acc[1][ct], 0, 0, 0);
            acc[0][ct] = __builtin_amdgcn_mfma_f32_16x16x32_bf16(alo[0], bhi, acc[0][ct], 0, 0, 0);
            acc[1][ct] = __builtin_amdgcn_mfma_f32_16x16x32_bf16(alo[1], bhi, acc[1][ct], 0, 0, 0);
            acc[0][ct] = __builtin_amdgcn_mfma_f32_16x16x32_bf16(ahi[0], blo, acc[0][ct], 0, 0, 0);
            acc[1][ct] = __builtin_amdgcn_mfma_f32_16x16x32_bf16(ahi[1], blo, acc[1][ct], 0, 0, 0);
        }
    }

#pragma unroll
    for (int rt = 0; rt < 2; ++rt) {
#pragma unroll
        for (int reg = 0; reg < 4; ++reg) {
            int row = rowBase + rt * 16 + lg * 4 + reg;
            if (row >= N) continue;
            if (MODE == 0) {
#pragma unroll
                for (int ct = 0; ct < 8; ++ct) {
                    int colc = ct * 16 + l15;
                    float v = acc[rt][ct][reg] + bias[colc];
                    v = v > 0.f ? v : expf(v) - 1.f;
                    ushort_t h = f2bf(v);
                    out0[(size_t)row * 128 + colc] = h;
                    out1[(size_t)row * 128 + colc] = f2bf(v - bf2f(h));
                }
            } else {
                float dv = dinv[row];
#pragma unroll
                for (int ct = 0; ct < 8; ++ct) {
                    int colc = ct * 16 + l15;
                    out0[(size_t)row * 128 + colc] = f2bf(acc[rt][ct][reg] * dv);
                }
            }
        }
    }
}

// ---------------- gather: h = split(elu(dinv[v]*(sum hwb[u] + hwb[v]) + bias)) ----------------
__global__ __launch_bounds__(256) void gather_agg(const int* __restrict__ rp,
                                                  const int* __restrict__ csrc,
                                                  const float* __restrict__ dinv,
                                                  const ushort_t* __restrict__ hwb,
                                                  const float* __restrict__ bias,
                                                  ushort_t* __restrict__ h_hi,
                                                  ushort_t* __restrict__ h_lo) {
    int v = blockIdx.x * 16 + (threadIdx.x >> 4);
    if (v >= NN) return;
    int c8 = (threadIdx.x & 15) << 3;
    int s = rp[v], e = rp[v + 1];
    float acc[8] = {};

    int i = s;
    for (; i + 8 <= e; i += 8) {
        int u[8];
#pragma unroll
        for (int k = 0; k < 8; ++k) u[k] = csrc[i + k];
        ushort8_t r[8];
#pragma unroll
        for (int k = 0; k < 8; ++k) r[k] = *(const ushort8_t*)(hwb + (size_t)u[k] * 128 + c8);
#pragma unroll
        for (int k = 0; k < 8; ++k)
#pragma unroll
            for (int j = 0; j < 8; ++j) acc[j] += bf2f(r[k][j]);
    }
    for (; i < e; ++i) {
        int u = csrc[i];
        ushort8_t r0 = *(const ushort8_t*)(hwb + (size_t)u * 128 + c8);
#pragma unroll
        for (int j = 0; j < 8; ++j) acc[j] += bf2f(r0[j]);
    }

    float di = dinv[v];
    ushort8_t sv = *(const ushort8_t*)(hwb + (size_t)v * 128 + c8);
    ushort8_t ohi, olo;
#pragma unroll
    for (int j = 0; j < 8; ++j) {
        float t = di * (acc[j] + bf2f(sv[j])) + bias[c8 + j];
        t = t > 0.f ? t : expf(t) - 1.f;
        ushort_t hh = f2bf(t);
        ohi[j] = hh;
        olo[j] = f2bf(t - bf2f(hh));
    }
    *(ushort8_t*)(h_hi + (size_t)v * 128 + c8) = ohi;
    *(ushort8_t*)(h_lo + (size_t)v * 128 + c8) = olo;
}

// ---------------- readout: 4 blocks per graph, atomic accumulate ----------------
__global__ __launch_bounds__(128) void readout(const ushort_t* __restrict__ h_hi,
                                               const ushort_t* __restrict__ h_lo,
                                               const int* __restrict__ batch,
                                               int n, float* __restrict__ reps) {
    int g = blockIdx.x >> 2;
    int part = blockIdx.x & 3;
    int lo = 0, hi = n;
    while (lo < hi) { int m = (lo + hi) >> 1; if (batch[m] < g) lo = m + 1; else hi = m; }
    int s = lo;
    lo = 0; hi = n;
    while (lo < hi) { int m = (lo + hi) >> 1; if (batch[m] < g + 1) lo = m + 1; else hi = m; }
    int e = lo;
    int c = threadIdx.x;
    float acc = 0.f;
    for (int v = s + part; v < e; v += 4) {
        size_t off = (size_t)v * 128 + c;
        acc += bf2f(h_hi[off]) + bf2f(h_lo[off]);
    }
    float cnt = (float)(e - s > 0 ? e - s : 1);
    unsafeAtomicAdd(&reps[(size_t)g * 128 + c], acc / cnt);
}

// ---------------- head GEMM (fp32 VALU, tiny) ----------------
__global__ __launch_bounds__(256) void gemm128(const float* __restrict__ A,
                                               const float* __restrict__ W,
                                               const float* __restrict__ bias,
                                               float* __restrict__ out,
                                               int N, int applyElu) {
    __shared__ float xs[64][128];
    __shared__ float ws[128][64];
    const int tid = threadIdx.x;
    const int rowBase = blockIdx.x * 64;
    const int colBase = blockIdx.y * 64;
#pragma unroll
    for (int it = 0; it < 8; ++it) {
        int idx = it * 256 + tid;
        int r = idx >> 5;
        int c4 = (idx & 31) << 2;
        int gr = rowBase + r;
        float4 v = make_float4(0.f, 0.f, 0.f, 0.f);
        if (gr < N) v = *(const float4*)(A + (size_t)gr * 128 + c4);
        *(float4*)(&xs[r][c4]) = v;
    }
#pragma unroll
    for (int it = 0; it < 8; ++it) {
        int idx = it * 256 + tid;
        int k = idx >> 4;
        int c4 = (idx & 15) << 2;
        *(float4*)(&ws[k][c4]) = *(const float4*)(W + (size_t)k * 128 + colBase + c4);
    }
    __syncthreads();
    const int rowg = tid >> 4, colg = tid & 15;
    const int r0 = rowg * 4, c0 = colg * 4;
    float acc[4][4] = {};
#pragma unroll 2
    for (int kb = 0; kb < 128; kb += 4) {
        float4 xr[4], wr[4];
#pragma unroll
        for (int i = 0; i < 4; ++i) xr[i] = *(const float4*)(&xs[r0 + i][kb]);
#pragma unroll
        for (int kk = 0; kk < 4; ++kk) wr[kk] = *(const float4*)(&ws[kb + kk][c0]);
#pragma unroll
        for (int i = 0; i < 4; ++i) {
            const float* xp = (const float*)&xr[i];
#pragma unroll
            for (int kk = 0; kk < 4; ++kk) {
                float xv = xp[kk];
                acc[i][0] = fmaf(xv, wr[kk].x, acc[i][0]);
                acc[i][1] = fmaf(xv, wr[kk].y, acc[i][1]);
                acc[i][2] = fmaf(xv, wr[kk].z, acc[i][2]);
                acc[i][3] = fmaf(xv, wr[kk].w, acc[i][3]);
            }
        }
    }
    float4 b4 = make_float4(0.f, 0.f, 0.f, 0.f);
    if (bias) b4 = *(const float4*)(bias + colBase + c0);
#pragma unroll
    for (int i = 0; i < 4; ++i) {
        int gr = rowBase + r0 + i;
        if (gr < N) {
            float4 o;
            o.x = acc[i][0] + b4.x;
            o.y = acc[i][1] + b4.y;
            o.z = acc[i][2] + b4.z;
            o.w = acc[i][3] + b4.w;
            if (applyElu) {
                o.x = o.x > 0.f ? o.x : expf(o.x) - 1.f;
                o.y = o.y > 0.f ? o.y : expf(o.y) - 1.f;
                o.z = o.z > 0.f ? o.z : expf(o.z) - 1.f;
                o.w = o.w > 0.f ? o.w : expf(o.w) - 1.f;
            }
            *(float4*)(out + (size_t)gr * 128 + colBase + c0) = o;
        }
    }
}

// ---------------- classifier + log_softmax ----------------
__global__ __launch_bounds__(64) void cls_logsoftmax(const float* __restrict__ g,
                                                     const float* __restrict__ cw,
                                                     const float* __restrict__ cb,
                                                     float* __restrict__ out) {
    int r = blockIdx.x;
    __shared__ float row[128];
    __shared__ float lg[10];
    int t = threadIdx.x;
    row[t] = g[(size_t)r * 128 + t];
    row[64 + t] = g[(size_t)r * 128 + 64 + t];
    __syncthreads();
    if (t < 10) {
        float a = cb[t];
        for (int k = 0; k < 128; ++k) a = fmaf(row[k], cw[k * 10 + t], a);
        lg[t] = a;
    }
    __syncthreads();
    if (t == 0) {
        float m = lg[0];
#pragma unroll
        for (int j = 1; j < 10; ++j) m = fmaxf(m, lg[j]);
        float se = 0.f;
#pragma unroll
        for (int j = 0; j < 10; ++j) se += expf(lg[j] - m);
        float L = logf(se);
#pragma unroll
        for (int j = 0; j < 10; ++j) out[(size_t)r * 10 + j] = lg[j] - m - L;
    }
}

extern "C" void kernel_launch(void* const* d_in, const int* in_sizes, int n_in,
                              void* d_out, int out_size, void* d_ws, size_t ws_size,
                              hipStream_t stream) {
    const float* x        = (const float*)d_in[0];
    const float* lin1_w   = (const float*)d_in[1];
    const float* lin1_b   = (const float*)d_in[2];
    const float* gcn_w    = (const float*)d_in[3];
    const float* gcn_b    = (const float*)d_in[4];
    const float* lin_out_w= (const float*)d_in[5];
    const float* lin_out_b= (const float*)d_in[6];
    const float* cls_w    = (const float*)d_in[7];
    const float* cls_b    = (const float*)d_in[8];
    const int*   ei       = (const int*)d_in[9];
    const int*   batch    = (const int*)d_in[10];
    float* out = (float*)d_out;

    const int* erow = ei;
    const int* ecol = ei + NE;

    ushort_t* h_hi  = (ushort_t*)d_ws;                     // NN*128 bf16
    ushort_t* h_lo  = h_hi + (size_t)NN * 128;             // NN*128 bf16
    ushort_t* hwb   = h_lo + (size_t)NN * 128;             // NN*128 bf16
    float*    dinv  = (float*)(hwb + (size_t)NN * 128);    // NN
    float*    reps  = dinv + NN;                           // NG*128
    float*    gbuf  = reps + (size_t)NG * 128;             // NG*128
    int*      rp    = (int*)(gbuf + (size_t)NG * 128);     // NN+1
    int*      csrc  = rp + NN + 1;                         // NE
    int*      ghist = csrc + NE;                           // NB
    int*      brp   = ghist + NB;                          // NB+1
    int*      gcur  = brp + NB + 1;                        // NB
    ushort_t* wt_hi = (ushort_t*)(gcur + NB);              // 4*16384
    ushort_t* wt_lo = wt_hi + 4 * 16384;                   // 4*16384
    int2*     pairs = (int2*)h_hi;                         // aliased: consumed before first gemm writes h_hi

    hipMemsetAsync(ghist, 0, NB * sizeof(int), stream);
    hipMemsetAsync(reps, 0, (size_t)NG * 128 * sizeof(float), stream);

    // ---- CSR build (bucketed) ----
    bucket_hist<<<512, 256, 0, stream>>>(ecol, ghist, NE);
    bucket_scan<<<1, NB, 0, stream>>>(ghist, brp, gcur, rp);
    partition_edges<<<(NE + CHUNK - 1) / CHUNK, 256, 0, stream>>>(erow, ecol, gcur, pairs, NE);
    bucket_fill<<<NB, 256, 0, stream>>>(pairs, brp, rp, dinv, csrc);
    prep_w<<<32, 256, 0, stream>>>(lin1_w, gcn_w, wt_hi, wt_lo);

    const int GEMM_GRID = (NN + 127) / 128;

    // h = elu(x @ lin1_w + b)  -> h_hi/h_lo   (overwrites pairs alias)
    gemm_mfma<true, 0><<<GEMM_GRID, 256, 0, stream>>>(x, nullptr, nullptr, wt_hi, wt_lo,
                                                      lin1_b, dinv, h_hi, h_lo, NN);
    readout<<<NG * 4, 128, 0, stream>>>(h_hi, h_lo, batch, NN, reps);

    for (int i = 0; i < 3; ++i) {
        gemm_mfma<false, 1><<<GEMM_GRID, 256, 0, stream>>>(nullptr, h_hi, h_lo,
                                                           wt_hi + (size_t)(i + 1) * 16384,
                                                           wt_lo + (size_t)(i + 1) * 16384,
                                                           nullptr, dinv, hwb, nullptr, NN);
        gather_agg<<<(NN + 15) / 16, 256, 0, stream>>>(rp, csrc, dinv, hwb,
                                                       gcn_b + (size_t)i * 128, h_hi, h_lo);
        readout<<<NG * 4, 128, 0, stream>>>(h_hi, h_lo, batch, NN, reps);
    }

    dim3 gs((NG + 63) / 64, 2);
    gemm128<<<gs, 256, 0, stream>>>(reps, lin_out_w, lin_out_b, gbuf, NG, 1);
    cls_logsoftmax<<<NG, 64, 0, stream>>>(gbuf, cls_w, cls_b, out);
}

// Round 7
// 564.866 us; speedup vs baseline: 1.0550x; 1.0550x over previous
//
#include <hip/hip_runtime.h>
#include <hip/hip_bf16.h>
#include <math.h>

#define NN 100000
#define NE 1600000
#define HID 128
#define NG 512
#define NB 512          // dst buckets
#define RB 196          // nodes per bucket (512*196 = 100352 >= NN)

typedef unsigned short ushort_t;
typedef __attribute__((ext_vector_type(8))) short bf16x8;
typedef __attribute__((ext_vector_type(8))) unsigned short ushort8_t;
typedef __attribute__((ext_vector_type(4))) float f32x4;

__device__ __forceinline__ ushort_t f2bf(float v) {
    unsigned u = __float_as_uint(v);
    unsigned r = (u + 0x7FFF + ((u >> 16) & 1)) >> 16;
    return (ushort_t)r;
}
__device__ __forceinline__ float bf2f(ushort_t u) {
    return __uint_as_float((unsigned)u << 16);
}

// ---------------- bucket histogram ----------------
__global__ __launch_bounds__(256) void bucket_hist(const int* __restrict__ ecol, int* __restrict__ ghist, int E) {
    __shared__ int lh[NB];
    for (int i = threadIdx.x; i < NB; i += 256) lh[i] = 0;
    __syncthreads();
    for (int e = blockIdx.x * 256 + threadIdx.x; e < E; e += gridDim.x * 256)
        atomicAdd(&lh[ecol[e] / RB], 1);
    __syncthreads();
    for (int i = threadIdx.x; i < NB; i += 256) {
        int c = lh[i];
        if (c) atomicAdd(&ghist[i], c);
    }
}

// ---------------- scan buckets ----------------
__global__ __launch_bounds__(NB) void bucket_scan(const int* __restrict__ ghist, int* __restrict__ brp,
                                                  int* __restrict__ gcur, int* __restrict__ rp) {
    __shared__ int s[NB];
    int t = threadIdx.x;
    int v = ghist[t];
    s[t] = v;
    __syncthreads();
    for (int off = 1; off < NB; off <<= 1) {
        int x = (t >= off) ? s[t - off] : 0;
        __syncthreads();
        s[t] += x;
        __syncthreads();
    }
    int ex = s[t] - v;
    brp[t] = ex;
    gcur[t] = ex;
    if (t == NB - 1) { brp[NB] = s[t]; rp[NN] = s[t]; }
}

// ---------------- partition edges into bucket-contiguous (src,dst) pairs ----------------
#define CHUNK 4096
__global__ __launch_bounds__(256) void partition_edges(const int* __restrict__ erow, const int* __restrict__ ecol,
                                                       int* __restrict__ gcur, int2* __restrict__ pairs, int E) {
    __shared__ int cnt[NB];
    __shared__ int base[NB];
    const int t = threadIdx.x;
    const int e0 = blockIdx.x * CHUNK;
    const int e1 = min(e0 + CHUNK, E);
    for (int i = t; i < NB; i += 256) cnt[i] = 0;
    __syncthreads();
    for (int e = e0 + t; e < e1; e += 256) atomicAdd(&cnt[ecol[e] / RB], 1);
    __syncthreads();
    for (int i = t; i < NB; i += 256) {
        int c = cnt[i];
        base[i] = c ? atomicAdd(&gcur[i], c) : 0;
        cnt[i] = 0;
    }
    __syncthreads();
    for (int e = e0 + t; e < e1; e += 256) {
        int d = ecol[e];
        int b = d / RB;
        int off = atomicAdd(&cnt[b], 1);
        pairs[base[b] + off] = make_int2(erow[e], d);
    }
}

// ---------------- per-bucket: degrees, dinv, rp, fill csrc ----------------
__global__ __launch_bounds__(256) void bucket_fill(const int2* __restrict__ pairs, const int* __restrict__ brp,
                                                   int* __restrict__ rp, float* __restrict__ dinv,
                                                   int* __restrict__ csrc) {
    __shared__ int cnt[RB];
    __shared__ int cur[RB];
    __shared__ int sc[256];
    const int b = blockIdx.x, t = threadIdx.x;
    const int nbase = b * RB;
    const int s = brp[b], e = brp[b + 1];
    for (int i = t; i < RB; i += 256) cnt[i] = 0;
    __syncthreads();
    for (int i = s + t; i < e; i += 256) atomicAdd(&cnt[pairs[i].y - nbase], 1);
    __syncthreads();
    int v = (t < RB) ? cnt[t] : 0;
    sc[t] = v;
    __syncthreads();
    for (int off = 1; off < 256; off <<= 1) {
        int x = (t >= off) ? sc[t - off] : 0;
        __syncthreads();
        sc[t] += x;
        __syncthreads();
    }
    if (t < RB) {
        int ex = s + sc[t] - v;
        int node = nbase + t;
        if (node < NN) {
            rp[node] = ex;
            dinv[node] = rsqrtf((float)v + 1.0f);
        }
        cur[t] = ex;
    }
    __syncthreads();
    for (int i = s + t; i < e; i += 256) {
        int2 p = pairs[i];
        int slot = atomicAdd(&cur[p.y - nbase], 1);
        csrc[slot] = p.x;
    }
}

// ---------------- weight prep: transpose + bf16 hi/lo split ----------------
__global__ __launch_bounds__(256) void prep_w(const float* __restrict__ lin1_w,
                                              const float* __restrict__ gcn_w,
                                              ushort_t* __restrict__ wt_hi,
                                              ushort_t* __restrict__ wt_lo) {
    int m = blockIdx.x >> 3;
    int chunk = blockIdx.x & 7;
    const float* W = (m == 0) ? lin1_w : gcn_w + (size_t)(m - 1) * 16384;
    ushort_t* hi = wt_hi + (size_t)m * 16384;
    ushort_t* lo = wt_lo + (size_t)m * 16384;
    for (int i = chunk * 2048 + threadIdx.x; i < (chunk + 1) * 2048; i += 256) {
        int k = i >> 7, n = i & 127;
        float v = W[i];
        ushort_t h = f2bf(v);
        ushort_t l = f2bf(v - bf2f(h));
        hi[n * 128 + k] = h;
        lo[n * 128 + k] = l;
    }
}

// ---------------- MFMA GEMM ----------------
// F32A=true : A fp32, 3-term split (x @ lin1_w), MODE 0.
// F32A=false: A bf16 exact, 2-term (W hi/lo only), MODE 1.
// MODE 0: out0 = bf16(elu(acc + bias)); MODE 1: out0 = bf16(dinv[row]*acc)
template<bool F32A, int MODE>
__global__ __launch_bounds__(256) void gemm_mfma(const float* __restrict__ A,
                                                 const ushort_t* __restrict__ a_bf,
                                                 const ushort_t* __restrict__ wt_hi,
                                                 const ushort_t* __restrict__ wt_lo,
                                                 const float* __restrict__ bias,
                                                 const float* __restrict__ dinv,
                                                 ushort_t* __restrict__ out0,
                                                 int N) {
    const int lane = threadIdx.x & 63;
    const int wid = threadIdx.x >> 6;
    const int rowBase = blockIdx.x * 128 + wid * 32;
    const int l15 = lane & 15, lg = lane >> 4;

    f32x4 acc[2][8];
#pragma unroll
    for (int rt = 0; rt < 2; ++rt)
#pragma unroll
        for (int ct = 0; ct < 8; ++ct) acc[rt][ct] = (f32x4){0.f, 0.f, 0.f, 0.f};

#pragma unroll
    for (int ks = 0; ks < 4; ++ks) {
        bf16x8 ahi[2], alo[2];
#pragma unroll
        for (int rt = 0; rt < 2; ++rt) {
            int r = rowBase + rt * 16 + l15;
            if (F32A) {
                float av[8];
                if (r < N) {
                    const float* ap = A + (size_t)r * 128 + ks * 32 + lg * 8;
                    float4 a0 = *(const float4*)(ap);
                    float4 a1 = *(const float4*)(ap + 4);
                    av[0] = a0.x; av[1] = a0.y; av[2] = a0.z; av[3] = a0.w;
                    av[4] = a1.x; av[5] = a1.y; av[6] = a1.z; av[7] = a1.w;
                } else {
#pragma unroll
                    for (int j = 0; j < 8; ++j) av[j] = 0.f;
                }
#pragma unroll
                for (int j = 0; j < 8; ++j) {
                    ushort_t h = f2bf(av[j]);
                    ahi[rt][j] = (short)h;
                    alo[rt][j] = (short)f2bf(av[j] - bf2f(h));
                }
            } else {
                if (r < N) {
                    ahi[rt] = *(const bf16x8*)(a_bf + (size_t)r * 128 + ks * 32 + lg * 8);
                } else {
                    bf16x8 z = {0, 0, 0, 0, 0, 0, 0, 0};
                    ahi[rt] = z;
                }
            }
        }
#pragma unroll
        for (int ct = 0; ct < 8; ++ct) {
            size_t boff = (size_t)(ct * 16 + l15) * 128 + ks * 32 + lg * 8;
            bf16x8 bhi = *(const bf16x8*)(wt_hi + boff);
            bf16x8 blo = *(const bf16x8*)(wt_lo + boff);
            acc[0][ct] = __builtin_amdgcn_mfma_f32_16x16x32_bf16(ahi[0], bhi, acc[0][ct], 0, 0, 0);
            acc[1][ct] = __builtin_amdgcn_mfma_f32_16x16x32_bf16(ahi[1], bhi, acc[1][ct], 0, 0, 0);
            acc[0][ct] = __builtin_amdgcn_mfma_f32_16x16x32_bf16(ahi[0], blo, acc[0][ct], 0, 0, 0);
            acc[1][ct] = __builtin_amdgcn_mfma_f32_16x16x32_bf16(ahi[1], blo, acc[1][ct], 0, 0, 0);
            if (F32A) {
                acc[0][ct] = __builtin_amdgcn_mfma_f32_16x16x32_bf16(alo[0], bhi, acc[0][ct], 0, 0, 0);
                acc[1][ct] = __builtin_amdgcn_mfma_f32_16x16x32_bf16(alo[1], bhi, acc[1][ct], 0, 0, 0);
            }
        }
    }

#pragma unroll
    for (int rt = 0; rt < 2; ++rt) {
#pragma unroll
        for (int reg = 0; reg < 4; ++reg) {
            int row = rowBase + rt * 16 + lg * 4 + reg;
            if (row >= N) continue;
            if (MODE == 0) {
#pragma unroll
                for (int ct = 0; ct < 8; ++ct) {
                    int colc = ct * 16 + l15;
                    float v = acc[rt][ct][reg] + bias[colc];
                    v = v > 0.f ? v : expf(v) - 1.f;
                    out0[(size_t)row * 128 + colc] = f2bf(v);
                }
            } else {
                float dv = dinv[row];
#pragma unroll
                for (int ct = 0; ct < 8; ++ct) {
                    int colc = ct * 16 + l15;
                    out0[(size_t)row * 128 + colc] = f2bf(acc[rt][ct][reg] * dv);
                }
            }
        }
    }
}

// ---------------- gather: h = bf16(elu(dinv[v]*(sum hwb[u] + hwb[v]) + bias)) ----------------
__global__ __launch_bounds__(256) void gather_agg(const int* __restrict__ rp,
                                                  const int* __restrict__ csrc,
                                                  const float* __restrict__ dinv,
                                                  const ushort_t* __restrict__ hwb,
                                                  const float* __restrict__ bias,
                                                  ushort_t* __restrict__ h_out) {
    int v = blockIdx.x * 16 + (threadIdx.x >> 4);
    if (v >= NN) return;
    int c8 = (threadIdx.x & 15) << 3;
    int s = rp[v], e = rp[v + 1];
    float acc[8] = {};

    int i = s;
    for (; i + 8 <= e; i += 8) {
        int u[8];
#pragma unroll
        for (int k = 0; k < 8; ++k) u[k] = csrc[i + k];
        ushort8_t r[8];
#pragma unroll
        for (int k = 0; k < 8; ++k) r[k] = *(const ushort8_t*)(hwb + (size_t)u[k] * 128 + c8);
#pragma unroll
        for (int k = 0; k < 8; ++k)
#pragma unroll
            for (int j = 0; j < 8; ++j) acc[j] += bf2f(r[k][j]);
    }
    for (; i < e; ++i) {
        int u = csrc[i];
        ushort8_t r0 = *(const ushort8_t*)(hwb + (size_t)u * 128 + c8);
#pragma unroll
        for (int j = 0; j < 8; ++j) acc[j] += bf2f(r0[j]);
    }

    float di = dinv[v];
    ushort8_t sv = *(const ushort8_t*)(hwb + (size_t)v * 128 + c8);
    ushort8_t o;
#pragma unroll
    for (int j = 0; j < 8; ++j) {
        float t = di * (acc[j] + bf2f(sv[j])) + bias[c8 + j];
        t = t > 0.f ? t : expf(t) - 1.f;
        o[j] = f2bf(t);
    }
    *(ushort8_t*)(h_out + (size_t)v * 128 + c8) = o;
}

// ---------------- readout: 4 blocks per graph, atomic accumulate ----------------
__global__ __launch_bounds__(128) void readout(const ushort_t* __restrict__ h,
                                               const int* __restrict__ batch,
                                               int n, float* __restrict__ reps) {
    int g = blockIdx.x >> 2;
    int part = blockIdx.x & 3;
    int lo = 0, hi = n;
    while (lo < hi) { int m = (lo + hi) >> 1; if (batch[m] < g) lo = m + 1; else hi = m; }
    int s = lo;
    lo = 0; hi = n;
    while (lo < hi) { int m = (lo + hi) >> 1; if (batch[m] < g + 1) lo = m + 1; else hi = m; }
    int e = lo;
    int c = threadIdx.x;
    float acc = 0.f;
    for (int v = s + part; v < e; v += 4) acc += bf2f(h[(size_t)v * 128 + c]);
    float cnt = (float)(e - s > 0 ? e - s : 1);
    unsafeAtomicAdd(&reps[(size_t)g * 128 + c], acc / cnt);
}

// ---------------- head GEMM (fp32 VALU, tiny) ----------------
__global__ __launch_bounds__(256) void gemm128(const float* __restrict__ A,
                                               const float* __restrict__ W,
                                               const float* __restrict__ bias,
                                               float* __restrict__ out,
                                               int N, int applyElu) {
    __shared__ float xs[64][128];
    __shared__ float ws[128][64];
    const int tid = threadIdx.x;
    const int rowBase = blockIdx.x * 64;
    const int colBase = blockIdx.y * 64;
#pragma unroll
    for (int it = 0; it < 8; ++it) {
        int idx = it * 256 + tid;
        int r = idx >> 5;
        int c4 = (idx & 31) << 2;
        int gr = rowBase + r;
        float4 v = make_float4(0.f, 0.f, 0.f, 0.f);
        if (gr < N) v = *(const float4*)(A + (size_t)gr * 128 + c4);
        *(float4*)(&xs[r][c4]) = v;
    }
#pragma unroll
    for (int it = 0; it < 8; ++it) {
        int idx = it * 256 + tid;
        int k = idx >> 4;
        int c4 = (idx & 15) << 2;
        *(float4*)(&ws[k][c4]) = *(const float4*)(W + (size_t)k * 128 + colBase + c4);
    }
    __syncthreads();
    const int rowg = tid >> 4, colg = tid & 15;
    const int r0 = rowg * 4, c0 = colg * 4;
    float acc[4][4] = {};
#pragma unroll 2
    for (int kb = 0; kb < 128; kb += 4) {
        float4 xr[4], wr[4];
#pragma unroll
        for (int i = 0; i < 4; ++i) xr[i] = *(const float4*)(&xs[r0 + i][kb]);
#pragma unroll
        for (int kk = 0; kk < 4; ++kk) wr[kk] = *(const float4*)(&ws[kb + kk][c0]);
#pragma unroll
        for (int i = 0; i < 4; ++i) {
            const float* xp = (const float*)&xr[i];
#pragma unroll
            for (int kk = 0; kk < 4; ++kk) {
                float xv = xp[kk];
                acc[i][0] = fmaf(xv, wr[kk].x, acc[i][0]);
                acc[i][1] = fmaf(xv, wr[kk].y, acc[i][1]);
                acc[i][2] = fmaf(xv, wr[kk].z, acc[i][2]);
                acc[i][3] = fmaf(xv, wr[kk].w, acc[i][3]);
            }
        }
    }
    float4 b4 = make_float4(0.f, 0.f, 0.f, 0.f);
    if (bias) b4 = *(const float4*)(bias + colBase + c0);
#pragma unroll
    for (int i = 0; i < 4; ++i) {
        int gr = rowBase + r0 + i;
        if (gr < N) {
            float4 o;
            o.x = acc[i][0] + b4.x;
            o.y = acc[i][1] + b4.y;
            o.z = acc[i][2] + b4.z;
            o.w = acc[i][3] + b4.w;
            if (applyElu) {
                o.x = o.x > 0.f ? o.x : expf(o.x) - 1.f;
                o.y = o.y > 0.f ? o.y : expf(o.y) - 1.f;
                o.z = o.z > 0.f ? o.z : expf(o.z) - 1.f;
                o.w = o.w > 0.f ? o.w : expf(o.w) - 1.f;
            }
            *(float4*)(out + (size_t)gr * 128 + colBase + c0) = o;
        }
    }
}

// ---------------- classifier + log_softmax ----------------
__global__ __launch_bounds__(64) void cls_logsoftmax(const float* __restrict__ g,
                                                     const float* __restrict__ cw,
                                                     const float* __restrict__ cb,
                                                     float* __restrict__ out) {
    int r = blockIdx.x;
    __shared__ float row[128];
    __shared__ float lg[10];
    int t = threadIdx.x;
    row[t] = g[(size_t)r * 128 + t];
    row[64 + t] = g[(size_t)r * 128 + 64 + t];
    __syncthreads();
    if (t < 10) {
        float a = cb[t];
        for (int k = 0; k < 128; ++k) a = fmaf(row[k], cw[k * 10 + t], a);
        lg[t] = a;
    }
    __syncthreads();
    if (t == 0) {
        float m = lg[0];
#pragma unroll
        for (int j = 1; j < 10; ++j) m = fmaxf(m, lg[j]);
        float se = 0.f;
#pragma unroll
        for (int j = 0; j < 10; ++j) se += expf(lg[j] - m);
        float L = logf(se);
#pragma unroll
        for (int j = 0; j < 10; ++j) out[(size_t)r * 10 + j] = lg[j] - m - L;
    }
}

extern "C" void kernel_launch(void* const* d_in, const int* in_sizes, int n_in,
                              void* d_out, int out_size, void* d_ws, size_t ws_size,
                              hipStream_t stream) {
    const float* x        = (const float*)d_in[0];
    const float* lin1_w   = (const float*)d_in[1];
    const float* lin1_b   = (const float*)d_in[2];
    const float* gcn_w    = (const float*)d_in[3];
    const float* gcn_b    = (const float*)d_in[4];
    const float* lin_out_w= (const float*)d_in[5];
    const float* lin_out_b= (const float*)d_in[6];
    const float* cls_w    = (const float*)d_in[7];
    const float* cls_b    = (const float*)d_in[8];
    const int*   ei       = (const int*)d_in[9];
    const int*   batch    = (const int*)d_in[10];
    float* out = (float*)d_out;

    const int* erow = ei;
    const int* ecol = ei + NE;

    ushort_t* h     = (ushort_t*)d_ws;                     // NN*128 bf16
    ushort_t* hwb   = h + (size_t)NN * 128;                // NN*128 bf16
    float*    dinv  = (float*)(hwb + (size_t)NN * 128);    // NN
    float*    reps  = dinv + NN;                           // NG*128
    float*    gbuf  = reps + (size_t)NG * 128;             // NG*128
    int*      rp    = (int*)(gbuf + (size_t)NG * 128);     // NN+1
    int*      csrc  = rp + NN + 1;                         // NE
    int*      ghist = csrc + NE;                           // NB
    int*      brp   = ghist + NB;                          // NB+1
    int*      gcur  = brp + NB + 1;                        // NB
    ushort_t* wt_hi = (ushort_t*)(gcur + NB);              // 4*16384
    ushort_t* wt_lo = wt_hi + 4 * 16384;                   // 4*16384
    int2*     pairs = (int2*)(wt_lo + 4 * 16384);          // NE (dedicated; no alias)

    hipMemsetAsync(ghist, 0, NB * sizeof(int), stream);
    hipMemsetAsync(reps, 0, (size_t)NG * 128 * sizeof(float), stream);

    // ---- CSR build (bucketed) ----
    bucket_hist<<<512, 256, 0, stream>>>(ecol, ghist, NE);
    bucket_scan<<<1, NB, 0, stream>>>(ghist, brp, gcur, rp);
    partition_edges<<<(NE + CHUNK - 1) / CHUNK, 256, 0, stream>>>(erow, ecol, gcur, pairs, NE);
    bucket_fill<<<NB, 256, 0, stream>>>(pairs, brp, rp, dinv, csrc);
    prep_w<<<32, 256, 0, stream>>>(lin1_w, gcn_w, wt_hi, wt_lo);

    const int GEMM_GRID = (NN + 127) / 128;

    // h = bf16(elu(x @ lin1_w + b))
    gemm_mfma<true, 0><<<GEMM_GRID, 256, 0, stream>>>(x, nullptr, wt_hi, wt_lo,
                                                      lin1_b, dinv, h, NN);
    readout<<<NG * 4, 128, 0, stream>>>(h, batch, NN, reps);

    for (int i = 0; i < 3; ++i) {
        gemm_mfma<false, 1><<<GEMM_GRID, 256, 0, stream>>>(nullptr, h,
                                                           wt_hi + (size_t)(i + 1) * 16384,
                                                           wt_lo + (size_t)(i + 1) * 16384,
                                                           nullptr, dinv, hwb, NN);
        gather_agg<<<(NN + 15) / 16, 256, 0, stream>>>(rp, csrc, dinv, hwb,
                                                       gcn_b + (size_t)i * 128, h);
        readout<<<NG * 4, 128, 0, stream>>>(h, batch, NN, reps);
    }

    dim3 gs((NG + 63) / 64, 2);
    gemm128<<<gs, 256, 0, stream>>>(reps, lin_out_w, lin_out_b, gbuf, NG, 1);
    cls_logsoftmax<<<NG, 64, 0, stream>>>(gbuf, cls_w, cls_b, out);
}

// Round 8
// 508.954 us; speedup vs baseline: 1.1709x; 1.1099x over previous
//
#include <hip/hip_runtime.h>
#include <hip/hip_bf16.h>
#include <math.h>

#define NN 100000
#define NE 1600000
#define HID 128
#define NG 512
#define NB 512          // dst buckets
#define RB 196          // nodes per bucket (512*196 = 100352 >= NN)

typedef unsigned short ushort_t;
typedef __attribute__((ext_vector_type(8))) short bf16x8;
typedef __attribute__((ext_vector_type(8))) unsigned short ushort8_t;
typedef __attribute__((ext_vector_type(4))) float f32x4;

__device__ __forceinline__ ushort_t f2bf(float v) {
    unsigned u = __float_as_uint(v);
    unsigned r = (u + 0x7FFF + ((u >> 16) & 1)) >> 16;
    return (ushort_t)r;
}
__device__ __forceinline__ float bf2f(ushort_t u) {
    return __uint_as_float((unsigned)u << 16);
}

// ---------------- bucket histogram ----------------
__global__ __launch_bounds__(256) void bucket_hist(const int* __restrict__ ecol, int* __restrict__ ghist, int E) {
    __shared__ int lh[NB];
    for (int i = threadIdx.x; i < NB; i += 256) lh[i] = 0;
    __syncthreads();
    for (int e = blockIdx.x * 256 + threadIdx.x; e < E; e += gridDim.x * 256)
        atomicAdd(&lh[ecol[e] / RB], 1);
    __syncthreads();
    for (int i = threadIdx.x; i < NB; i += 256) {
        int c = lh[i];
        if (c) atomicAdd(&ghist[i], c);
    }
}

// ---------------- scan buckets ----------------
__global__ __launch_bounds__(NB) void bucket_scan(const int* __restrict__ ghist, int* __restrict__ brp,
                                                  int* __restrict__ gcur, int* __restrict__ rp) {
    __shared__ int s[NB];
    int t = threadIdx.x;
    int v = ghist[t];
    s[t] = v;
    __syncthreads();
    for (int off = 1; off < NB; off <<= 1) {
        int x = (t >= off) ? s[t - off] : 0;
        __syncthreads();
        s[t] += x;
        __syncthreads();
    }
    int ex = s[t] - v;
    brp[t] = ex;
    gcur[t] = ex;
    if (t == NB - 1) { brp[NB] = s[t]; rp[NN] = s[t]; }
}

// ---------------- partition edges into bucket-contiguous (src,dst) pairs ----------------
#define CHUNK 4096
__global__ __launch_bounds__(256) void partition_edges(const int* __restrict__ erow, const int* __restrict__ ecol,
                                                       int* __restrict__ gcur, int2* __restrict__ pairs, int E) {
    __shared__ int cnt[NB];
    __shared__ int base[NB];
    const int t = threadIdx.x;
    const int e0 = blockIdx.x * CHUNK;
    const int e1 = min(e0 + CHUNK, E);
    for (int i = t; i < NB; i += 256) cnt[i] = 0;
    __syncthreads();
    for (int e = e0 + t; e < e1; e += 256) atomicAdd(&cnt[ecol[e] / RB], 1);
    __syncthreads();
    for (int i = t; i < NB; i += 256) {
        int c = cnt[i];
        base[i] = c ? atomicAdd(&gcur[i], c) : 0;
        cnt[i] = 0;
    }
    __syncthreads();
    for (int e = e0 + t; e < e1; e += 256) {
        int d = ecol[e];
        int b = d / RB;
        int off = atomicAdd(&cnt[b], 1);
        pairs[base[b] + off] = make_int2(erow[e], d);
    }
}

// ---------------- per-bucket: degrees, dinv, rp, fill csrc ----------------
__global__ __launch_bounds__(256) void bucket_fill(const int2* __restrict__ pairs, const int* __restrict__ brp,
                                                   int* __restrict__ rp, float* __restrict__ dinv,
                                                   int* __restrict__ csrc) {
    __shared__ int cnt[RB];
    __shared__ int cur[RB];
    __shared__ int sc[256];
    const int b = blockIdx.x, t = threadIdx.x;
    const int nbase = b * RB;
    const int s = brp[b], e = brp[b + 1];
    for (int i = t; i < RB; i += 256) cnt[i] = 0;
    __syncthreads();
    for (int i = s + t; i < e; i += 256) atomicAdd(&cnt[pairs[i].y - nbase], 1);
    __syncthreads();
    int v = (t < RB) ? cnt[t] : 0;
    sc[t] = v;
    __syncthreads();
    for (int off = 1; off < 256; off <<= 1) {
        int x = (t >= off) ? sc[t - off] : 0;
        __syncthreads();
        sc[t] += x;
        __syncthreads();
    }
    if (t < RB) {
        int ex = s + sc[t] - v;
        int node = nbase + t;
        if (node < NN) {
            rp[node] = ex;
            dinv[node] = rsqrtf((float)v + 1.0f);
        }
        cur[t] = ex;
    }
    __syncthreads();
    for (int i = s + t; i < e; i += 256) {
        int2 p = pairs[i];
        int slot = atomicAdd(&cur[p.y - nbase], 1);
        csrc[slot] = p.x;
    }
}

// ---------------- weight prep: bf16 hi/lo split in MFMA FRAGMENT layout ----------------
// packed index i: j=i&7, lane=(i>>3)&63, ks=(i>>9)&3, ct=(i>>11)&7
// fragment element = Wt[n][k] with n = ct*16 + (lane&15), k = ks*32 + (lane>>4)*8 + j
// so the GEMM's B-load at offset ((ct*4+ks)*64+lane)*8 is lane-contiguous (coalesced).
__global__ __launch_bounds__(256) void prep_w(const float* __restrict__ lin1_w,
                                              const float* __restrict__ gcn_w,
                                              ushort_t* __restrict__ wt_hi,
                                              ushort_t* __restrict__ wt_lo) {
    int m = blockIdx.x >> 3;
    int chunk = blockIdx.x & 7;
    const float* W = (m == 0) ? lin1_w : gcn_w + (size_t)(m - 1) * 16384;
    ushort_t* hi = wt_hi + (size_t)m * 16384;
    ushort_t* lo = wt_lo + (size_t)m * 16384;
    for (int i = chunk * 2048 + threadIdx.x; i < (chunk + 1) * 2048; i += 256) {
        int j = i & 7;
        int lane = (i >> 3) & 63;
        int ks = (i >> 9) & 3;
        int ct = (i >> 11) & 7;
        int n = ct * 16 + (lane & 15);
        int k = ks * 32 + (lane >> 4) * 8 + j;
        float v = W[k * 128 + n];
        ushort_t h = f2bf(v);
        hi[i] = h;
        lo[i] = f2bf(v - bf2f(h));
    }
}

// ---------------- MFMA GEMM ----------------
// F32A=true : A fp32, 3-term split (x @ lin1_w), MODE 0.
// F32A=false: A bf16 exact, 2-term (W hi/lo only), MODE 1.
// MODE 0: out0 = bf16(elu(acc + bias)); MODE 1: out0 = bf16(dinv[row]*acc)
template<bool F32A, int MODE>
__global__ __launch_bounds__(256) void gemm_mfma(const float* __restrict__ A,
                                                 const ushort_t* __restrict__ a_bf,
                                                 const ushort_t* __restrict__ wt_hi,
                                                 const ushort_t* __restrict__ wt_lo,
                                                 const float* __restrict__ bias,
                                                 const float* __restrict__ dinv,
                                                 ushort_t* __restrict__ out0,
                                                 int N) {
    const int lane = threadIdx.x & 63;
    const int wid = threadIdx.x >> 6;
    const int rowBase = blockIdx.x * 128 + wid * 32;
    const int l15 = lane & 15, lg = lane >> 4;

    f32x4 acc[2][8];
#pragma unroll
    for (int rt = 0; rt < 2; ++rt)
#pragma unroll
        for (int ct = 0; ct < 8; ++ct) acc[rt][ct] = (f32x4){0.f, 0.f, 0.f, 0.f};

#pragma unroll
    for (int ks = 0; ks < 4; ++ks) {
        bf16x8 ahi[2], alo[2];
#pragma unroll
        for (int rt = 0; rt < 2; ++rt) {
            int r = rowBase + rt * 16 + l15;
            if (F32A) {
                float av[8];
                if (r < N) {
                    const float* ap = A + (size_t)r * 128 + ks * 32 + lg * 8;
                    float4 a0 = *(const float4*)(ap);
                    float4 a1 = *(const float4*)(ap + 4);
                    av[0] = a0.x; av[1] = a0.y; av[2] = a0.z; av[3] = a0.w;
                    av[4] = a1.x; av[5] = a1.y; av[6] = a1.z; av[7] = a1.w;
                } else {
#pragma unroll
                    for (int j = 0; j < 8; ++j) av[j] = 0.f;
                }
#pragma unroll
                for (int j = 0; j < 8; ++j) {
                    ushort_t h = f2bf(av[j]);
                    ahi[rt][j] = (short)h;
                    alo[rt][j] = (short)f2bf(av[j] - bf2f(h));
                }
            } else {
                if (r < N) {
                    ahi[rt] = *(const bf16x8*)(a_bf + (size_t)r * 128 + ks * 32 + lg * 8);
                } else {
                    bf16x8 z = {0, 0, 0, 0, 0, 0, 0, 0};
                    ahi[rt] = z;
                }
            }
        }
#pragma unroll
        for (int ct = 0; ct < 8; ++ct) {
            // fragment-packed: lane-contiguous (fully coalesced 1 KB wave-load)
            size_t boff = (size_t)(((ct * 4 + ks) * 64 + lane) * 8);
            bf16x8 bhi = *(const bf16x8*)(wt_hi + boff);
            bf16x8 blo = *(const bf16x8*)(wt_lo + boff);
            acc[0][ct] = __builtin_amdgcn_mfma_f32_16x16x32_bf16(ahi[0], bhi, acc[0][ct], 0, 0, 0);
            acc[1][ct] = __builtin_amdgcn_mfma_f32_16x16x32_bf16(ahi[1], bhi, acc[1][ct], 0, 0, 0);
            acc[0][ct] = __builtin_amdgcn_mfma_f32_16x16x32_bf16(ahi[0], blo, acc[0][ct], 0, 0, 0);
            acc[1][ct] = __builtin_amdgcn_mfma_f32_16x16x32_bf16(ahi[1], blo, acc[1][ct], 0, 0, 0);
            if (F32A) {
                acc[0][ct] = __builtin_amdgcn_mfma_f32_16x16x32_bf16(alo[0], bhi, acc[0][ct], 0, 0, 0);
                acc[1][ct] = __builtin_amdgcn_mfma_f32_16x16x32_bf16(alo[1], bhi, acc[1][ct], 0, 0, 0);
            }
        }
    }

#pragma unroll
    for (int rt = 0; rt < 2; ++rt) {
#pragma unroll
        for (int reg = 0; reg < 4; ++reg) {
            int row = rowBase + rt * 16 + lg * 4 + reg;
            if (row >= N) continue;
            if (MODE == 0) {
#pragma unroll
                for (int ct = 0; ct < 8; ++ct) {
                    int colc = ct * 16 + l15;
                    float v = acc[rt][ct][reg] + bias[colc];
                    v = v > 0.f ? v : expf(v) - 1.f;
                    out0[(size_t)row * 128 + colc] = f2bf(v);
                }
            } else {
                float dv = dinv[row];
#pragma unroll
                for (int ct = 0; ct < 8; ++ct) {
                    int colc = ct * 16 + l15;
                    out0[(size_t)row * 128 + colc] = f2bf(acc[rt][ct][reg] * dv);
                }
            }
        }
    }
}

// ---------------- gather: h = bf16(elu(dinv[v]*(sum hwb[u] + hwb[v]) + bias)) ----------------
__global__ __launch_bounds__(256) void gather_agg(const int* __restrict__ rp,
                                                  const int* __restrict__ csrc,
                                                  const float* __restrict__ dinv,
                                                  const ushort_t* __restrict__ hwb,
                                                  const float* __restrict__ bias,
                                                  ushort_t* __restrict__ h_out) {
    int v = blockIdx.x * 16 + (threadIdx.x >> 4);
    if (v >= NN) return;
    int c8 = (threadIdx.x & 15) << 3;
    int s = rp[v], e = rp[v + 1];
    float acc[8] = {};

    int i = s;
    for (; i + 8 <= e; i += 8) {
        int u[8];
#pragma unroll
        for (int k = 0; k < 8; ++k) u[k] = csrc[i + k];
        ushort8_t r[8];
#pragma unroll
        for (int k = 0; k < 8; ++k) r[k] = *(const ushort8_t*)(hwb + (size_t)u[k] * 128 + c8);
#pragma unroll
        for (int k = 0; k < 8; ++k)
#pragma unroll
            for (int j = 0; j < 8; ++j) acc[j] += bf2f(r[k][j]);
    }
    for (; i < e; ++i) {
        int u = csrc[i];
        ushort8_t r0 = *(const ushort8_t*)(hwb + (size_t)u * 128 + c8);
#pragma unroll
        for (int j = 0; j < 8; ++j) acc[j] += bf2f(r0[j]);
    }

    float di = dinv[v];
    ushort8_t sv = *(const ushort8_t*)(hwb + (size_t)v * 128 + c8);
    ushort8_t o;
#pragma unroll
    for (int j = 0; j < 8; ++j) {
        float t = di * (acc[j] + bf2f(sv[j])) + bias[c8 + j];
        t = t > 0.f ? t : expf(t) - 1.f;
        o[j] = f2bf(t);
    }
    *(ushort8_t*)(h_out + (size_t)v * 128 + c8) = o;
}

// ---------------- readout: 4 blocks per graph, atomic accumulate ----------------
__global__ __launch_bounds__(128) void readout(const ushort_t* __restrict__ h,
                                               const int* __restrict__ batch,
                                               int n, float* __restrict__ reps) {
    int g = blockIdx.x >> 2;
    int part = blockIdx.x & 3;
    int lo = 0, hi = n;
    while (lo < hi) { int m = (lo + hi) >> 1; if (batch[m] < g) lo = m + 1; else hi = m; }
    int s = lo;
    lo = 0; hi = n;
    while (lo < hi) { int m = (lo + hi) >> 1; if (batch[m] < g + 1) lo = m + 1; else hi = m; }
    int e = lo;
    int c = threadIdx.x;
    float acc = 0.f;
    for (int v = s + part; v < e; v += 4) acc += bf2f(h[(size_t)v * 128 + c]);
    float cnt = (float)(e - s > 0 ? e - s : 1);
    unsafeAtomicAdd(&reps[(size_t)g * 128 + c], acc / cnt);
}

// ---------------- head GEMM (fp32 VALU, tiny) ----------------
__global__ __launch_bounds__(256) void gemm128(const float* __restrict__ A,
                                               const float* __restrict__ W,
                                               const float* __restrict__ bias,
                                               float* __restrict__ out,
                                               int N, int applyElu) {
    __shared__ float xs[64][128];
    __shared__ float ws[128][64];
    const int tid = threadIdx.x;
    const int rowBase = blockIdx.x * 64;
    const int colBase = blockIdx.y * 64;
#pragma unroll
    for (int it = 0; it < 8; ++it) {
        int idx = it * 256 + tid;
        int r = idx >> 5;
        int c4 = (idx & 31) << 2;
        int gr = rowBase + r;
        float4 v = make_float4(0.f, 0.f, 0.f, 0.f);
        if (gr < N) v = *(const float4*)(A + (size_t)gr * 128 + c4);
        *(float4*)(&xs[r][c4]) = v;
    }
#pragma unroll
    for (int it = 0; it < 8; ++it) {
        int idx = it * 256 + tid;
        int k = idx >> 4;
        int c4 = (idx & 15) << 2;
        *(float4*)(&ws[k][c4]) = *(const float4*)(W + (size_t)k * 128 + colBase + c4);
    }
    __syncthreads();
    const int rowg = tid >> 4, colg = tid & 15;
    const int r0 = rowg * 4, c0 = colg * 4;
    float acc[4][4] = {};
#pragma unroll 2
    for (int kb = 0; kb < 128; kb += 4) {
        float4 xr[4], wr[4];
#pragma unroll
        for (int i = 0; i < 4; ++i) xr[i] = *(const float4*)(&xs[r0 + i][kb]);
#pragma unroll
        for (int kk = 0; kk < 4; ++kk) wr[kk] = *(const float4*)(&ws[kb + kk][c0]);
#pragma unroll
        for (int i = 0; i < 4; ++i) {
            const float* xp = (const float*)&xr[i];
#pragma unroll
            for (int kk = 0; kk < 4; ++kk) {
                float xv = xp[kk];
                acc[i][0] = fmaf(xv, wr[kk].x, acc[i][0]);
                acc[i][1] = fmaf(xv, wr[kk].y, acc[i][1]);
                acc[i][2] = fmaf(xv, wr[kk].z, acc[i][2]);
                acc[i][3] = fmaf(xv, wr[kk].w, acc[i][3]);
            }
        }
    }
    float4 b4 = make_float4(0.f, 0.f, 0.f, 0.f);
    if (bias) b4 = *(const float4*)(bias + colBase + c0);
#pragma unroll
    for (int i = 0; i < 4; ++i) {
        int gr = rowBase + r0 + i;
        if (gr < N) {
            float4 o;
            o.x = acc[i][0] + b4.x;
            o.y = acc[i][1] + b4.y;
            o.z = acc[i][2] + b4.z;
            o.w = acc[i][3] + b4.w;
            if (applyElu) {
                o.x = o.x > 0.f ? o.x : expf(o.x) - 1.f;
                o.y = o.y > 0.f ? o.y : expf(o.y) - 1.f;
                o.z = o.z > 0.f ? o.z : expf(o.z) - 1.f;
                o.w = o.w > 0.f ? o.w : expf(o.w) - 1.f;
            }
            *(float4*)(out + (size_t)gr * 128 + colBase + c0) = o;
        }
    }
}

// ---------------- classifier + log_softmax ----------------
__global__ __launch_bounds__(64) void cls_logsoftmax(const float* __restrict__ g,
                                                     const float* __restrict__ cw,
                                                     const float* __restrict__ cb,
                                                     float* __restrict__ out) {
    int r = blockIdx.x;
    __shared__ float row[128];
    __shared__ float lg[10];
    int t = threadIdx.x;
    row[t] = g[(size_t)r * 128 + t];
    row[64 + t] = g[(size_t)r * 128 + 64 + t];
    __syncthreads();
    if (t < 10) {
        float a = cb[t];
        for (int k = 0; k < 128; ++k) a = fmaf(row[k], cw[k * 10 + t], a);
        lg[t] = a;
    }
    __syncthreads();
    if (t == 0) {
        float m = lg[0];
#pragma unroll
        for (int j = 1; j < 10; ++j) m = fmaxf(m, lg[j]);
        float se = 0.f;
#pragma unroll
        for (int j = 0; j < 10; ++j) se += expf(lg[j] - m);
        float L = logf(se);
#pragma unroll
        for (int j = 0; j < 10; ++j) out[(size_t)r * 10 + j] = lg[j] - m - L;
    }
}

extern "C" void kernel_launch(void* const* d_in, const int* in_sizes, int n_in,
                              void* d_out, int out_size, void* d_ws, size_t ws_size,
                              hipStream_t stream) {
    const float* x        = (const float*)d_in[0];
    const float* lin1_w   = (const float*)d_in[1];
    const float* lin1_b   = (const float*)d_in[2];
    const float* gcn_w    = (const float*)d_in[3];
    const float* gcn_b    = (const float*)d_in[4];
    const float* lin_out_w= (const float*)d_in[5];
    const float* lin_out_b= (const float*)d_in[6];
    const float* cls_w    = (const float*)d_in[7];
    const float* cls_b    = (const float*)d_in[8];
    const int*   ei       = (const int*)d_in[9];
    const int*   batch    = (const int*)d_in[10];
    float* out = (float*)d_out;

    const int* erow = ei;
    const int* ecol = ei + NE;

    ushort_t* h     = (ushort_t*)d_ws;                     // NN*128 bf16
    ushort_t* hwb   = h + (size_t)NN * 128;                // NN*128 bf16
    float*    dinv  = (float*)(hwb + (size_t)NN * 128);    // NN
    float*    reps  = dinv + NN;                           // NG*128
    float*    gbuf  = reps + (size_t)NG * 128;             // NG*128
    int*      rp    = (int*)(gbuf + (size_t)NG * 128);     // NN+1
    int*      csrc  = rp + NN + 1;                         // NE
    int*      ghist = csrc + NE;                           // NB
    int*      brp   = ghist + NB;                          // NB+1
    int*      gcur  = brp + NB + 1;                        // NB
    ushort_t* wt_hi = (ushort_t*)(gcur + NB);              // 4*16384
    ushort_t* wt_lo = wt_hi + 4 * 16384;                   // 4*16384
    int2*     pairs = (int2*)(wt_lo + 4 * 16384);          // NE

    hipMemsetAsync(ghist, 0, NB * sizeof(int), stream);
    hipMemsetAsync(reps, 0, (size_t)NG * 128 * sizeof(float), stream);

    // ---- CSR build (bucketed) ----
    bucket_hist<<<512, 256, 0, stream>>>(ecol, ghist, NE);
    bucket_scan<<<1, NB, 0, stream>>>(ghist, brp, gcur, rp);
    partition_edges<<<(NE + CHUNK - 1) / CHUNK, 256, 0, stream>>>(erow, ecol, gcur, pairs, NE);
    bucket_fill<<<NB, 256, 0, stream>>>(pairs, brp, rp, dinv, csrc);
    prep_w<<<32, 256, 0, stream>>>(lin1_w, gcn_w, wt_hi, wt_lo);

    const int GEMM_GRID = (NN + 127) / 128;

    // h = bf16(elu(x @ lin1_w + b))
    gemm_mfma<true, 0><<<GEMM_GRID, 256, 0, stream>>>(x, nullptr, wt_hi, wt_lo,
                                                      lin1_b, dinv, h, NN);
    readout<<<NG * 4, 128, 0, stream>>>(h, batch, NN, reps);

    for (int i = 0; i < 3; ++i) {
        gemm_mfma<false, 1><<<GEMM_GRID, 256, 0, stream>>>(nullptr, h,
                                                           wt_hi + (size_t)(i + 1) * 16384,
                                                           wt_lo + (size_t)(i + 1) * 16384,
                                                           nullptr, dinv, hwb, NN);
        gather_agg<<<(NN + 15) / 16, 256, 0, stream>>>(rp, csrc, dinv, hwb,
                                                       gcn_b + (size_t)i * 128, h);
        readout<<<NG * 4, 128, 0, stream>>>(h, batch, NN, reps);
    }

    dim3 gs((NG + 63) / 64, 2);
    gemm128<<<gs, 256, 0, stream>>>(reps, lin_out_w, lin_out_b, gbuf, NG, 1);
    cls_logsoftmax<<<NG, 64, 0, stream>>>(gbuf, cls_w, cls_b, out);
}

// Round 9
// 455.445 us; speedup vs baseline: 1.3085x; 1.1175x over previous
//
#include <hip/hip_runtime.h>
#include <hip/hip_bf16.h>
#include <math.h>

#define NN 100000
#define NE 1600000
#define HID 128
#define NG 512
#define NB 512          // dst buckets
#define RB 196          // nodes per bucket (512*196 = 100352 >= NN)

typedef unsigned short ushort_t;
typedef __attribute__((ext_vector_type(8))) short bf16x8;
typedef __attribute__((ext_vector_type(8))) unsigned short ushort8_t;
typedef __attribute__((ext_vector_type(4))) float f32x4;

__device__ __forceinline__ ushort_t f2bf(float v) {
    unsigned u = __float_as_uint(v);
    unsigned r = (u + 0x7FFF + ((u >> 16) & 1)) >> 16;
    return (ushort_t)r;
}
__device__ __forceinline__ float bf2f(ushort_t u) {
    return __uint_as_float((unsigned)u << 16);
}

// ---------------- bucket histogram (blocks 0..511) + weight prep (blocks 512..543) ----------------
__global__ __launch_bounds__(256) void hist_and_prepw(const int* __restrict__ ecol, int* __restrict__ ghist, int E,
                                                      const float* __restrict__ lin1_w,
                                                      const float* __restrict__ gcn_w,
                                                      ushort_t* __restrict__ wt_hi,
                                                      ushort_t* __restrict__ wt_lo) {
    if (blockIdx.x < 512) {
        __shared__ int lh[NB];
        for (int i = threadIdx.x; i < NB; i += 256) lh[i] = 0;
        __syncthreads();
        for (int e = blockIdx.x * 256 + threadIdx.x; e < E; e += 512 * 256)
            atomicAdd(&lh[ecol[e] / RB], 1);
        __syncthreads();
        for (int i = threadIdx.x; i < NB; i += 256) {
            int c = lh[i];
            if (c) atomicAdd(&ghist[i], c);
        }
    } else {
        // prep_w: bf16 hi/lo split in MFMA fragment layout
        int mb = blockIdx.x - 512;
        int m = mb >> 3;
        int chunk = mb & 7;
        const float* W = (m == 0) ? lin1_w : gcn_w + (size_t)(m - 1) * 16384;
        ushort_t* hi = wt_hi + (size_t)m * 16384;
        ushort_t* lo = wt_lo + (size_t)m * 16384;
        for (int i = chunk * 2048 + threadIdx.x; i < (chunk + 1) * 2048; i += 256) {
            int j = i & 7;
            int lane = (i >> 3) & 63;
            int ks = (i >> 9) & 3;
            int ct = (i >> 11) & 7;
            int n = ct * 16 + (lane & 15);
            int k = ks * 32 + (lane >> 4) * 8 + j;
            float v = W[k * 128 + n];
            ushort_t h = f2bf(v);
            hi[i] = h;
            lo[i] = f2bf(v - bf2f(h));
        }
    }
}

// ---------------- scan buckets ----------------
__global__ __launch_bounds__(NB) void bucket_scan(const int* __restrict__ ghist, int* __restrict__ brp,
                                                  int* __restrict__ gcur, int* __restrict__ rp) {
    __shared__ int s[NB];
    int t = threadIdx.x;
    int v = ghist[t];
    s[t] = v;
    __syncthreads();
    for (int off = 1; off < NB; off <<= 1) {
        int x = (t >= off) ? s[t - off] : 0;
        __syncthreads();
        s[t] += x;
        __syncthreads();
    }
    int ex = s[t] - v;
    brp[t] = ex;
    gcur[t] = ex;
    if (t == NB - 1) { brp[NB] = s[t]; rp[NN] = s[t]; }
}

// ---------------- partition edges into bucket-contiguous packed ints ----------------
// packed = (src << 8) | (dst - bucket*RB);  src < 2^17, dloc < 196 < 2^8
#define CHUNK 4096
__global__ __launch_bounds__(256) void partition_edges(const int* __restrict__ erow, const int* __restrict__ ecol,
                                                       int* __restrict__ gcur, unsigned int* __restrict__ pairs, int E) {
    __shared__ int cnt[NB];
    __shared__ int base[NB];
    const int t = threadIdx.x;
    const int e0 = blockIdx.x * CHUNK;
    const int e1 = min(e0 + CHUNK, E);
    for (int i = t; i < NB; i += 256) cnt[i] = 0;
    __syncthreads();
    for (int e = e0 + t; e < e1; e += 256) atomicAdd(&cnt[ecol[e] / RB], 1);
    __syncthreads();
    for (int i = t; i < NB; i += 256) {
        int c = cnt[i];
        base[i] = c ? atomicAdd(&gcur[i], c) : 0;
        cnt[i] = 0;
    }
    __syncthreads();
    for (int e = e0 + t; e < e1; e += 256) {
        int d = ecol[e];
        int b = d / RB;
        int off = atomicAdd(&cnt[b], 1);
        pairs[base[b] + off] = ((unsigned)erow[e] << 8) | (unsigned)(d - b * RB);
    }
}

// ---------------- per-bucket: degrees, dinv, rp, fill csrc ----------------
__global__ __launch_bounds__(256) void bucket_fill(const unsigned int* __restrict__ pairs, const int* __restrict__ brp,
                                                   int* __restrict__ rp, float* __restrict__ dinv,
                                                   int* __restrict__ csrc) {
    __shared__ int cnt[RB];
    __shared__ int cur[RB];
    __shared__ int sc[256];
    const int b = blockIdx.x, t = threadIdx.x;
    const int nbase = b * RB;
    const int s = brp[b], e = brp[b + 1];
    for (int i = t; i < RB; i += 256) cnt[i] = 0;
    __syncthreads();
    for (int i = s + t; i < e; i += 256) atomicAdd(&cnt[pairs[i] & 255u], 1);
    __syncthreads();
    int v = (t < RB) ? cnt[t] : 0;
    sc[t] = v;
    __syncthreads();
    for (int off = 1; off < 256; off <<= 1) {
        int x = (t >= off) ? sc[t - off] : 0;
        __syncthreads();
        sc[t] += x;
        __syncthreads();
    }
    if (t < RB) {
        int ex = s + sc[t] - v;
        int node = nbase + t;
        if (node < NN) {
            rp[node] = ex;
            dinv[node] = rsqrtf((float)v + 1.0f);
        }
        cur[t] = ex;
    }
    __syncthreads();
    for (int i = s + t; i < e; i += 256) {
        unsigned int p = pairs[i];
        int slot = atomicAdd(&cur[p & 255u], 1);
        csrc[slot] = (int)(p >> 8);
    }
}

// ---------------- MFMA GEMM ----------------
// F32A=true : A fp32, 3-term split (x @ lin1_w), MODE 0.
// F32A=false: A bf16 exact, 2-term (W hi/lo only), MODE 1.
// MODE 0: out0 = bf16(elu(acc + bias)); MODE 1: out0 = bf16(dinv[row]*acc)
template<bool F32A, int MODE>
__global__ __launch_bounds__(256) void gemm_mfma(const float* __restrict__ A,
                                                 const ushort_t* __restrict__ a_bf,
                                                 const ushort_t* __restrict__ wt_hi,
                                                 const ushort_t* __restrict__ wt_lo,
                                                 const float* __restrict__ bias,
                                                 const float* __restrict__ dinv,
                                                 ushort_t* __restrict__ out0,
                                                 int N) {
    const int lane = threadIdx.x & 63;
    const int wid = threadIdx.x >> 6;
    const int rowBase = blockIdx.x * 128 + wid * 32;
    const int l15 = lane & 15, lg = lane >> 4;

    f32x4 acc[2][8];
#pragma unroll
    for (int rt = 0; rt < 2; ++rt)
#pragma unroll
        for (int ct = 0; ct < 8; ++ct) acc[rt][ct] = (f32x4){0.f, 0.f, 0.f, 0.f};

#pragma unroll
    for (int ks = 0; ks < 4; ++ks) {
        bf16x8 ahi[2], alo[2];
#pragma unroll
        for (int rt = 0; rt < 2; ++rt) {
            int r = rowBase + rt * 16 + l15;
            if (F32A) {
                float av[8];
                if (r < N) {
                    const float* ap = A + (size_t)r * 128 + ks * 32 + lg * 8;
                    float4 a0 = *(const float4*)(ap);
                    float4 a1 = *(const float4*)(ap + 4);
                    av[0] = a0.x; av[1] = a0.y; av[2] = a0.z; av[3] = a0.w;
                    av[4] = a1.x; av[5] = a1.y; av[6] = a1.z; av[7] = a1.w;
                } else {
#pragma unroll
                    for (int j = 0; j < 8; ++j) av[j] = 0.f;
                }
#pragma unroll
                for (int j = 0; j < 8; ++j) {
                    ushort_t h = f2bf(av[j]);
                    ahi[rt][j] = (short)h;
                    alo[rt][j] = (short)f2bf(av[j] - bf2f(h));
                }
            } else {
                if (r < N) {
                    ahi[rt] = *(const bf16x8*)(a_bf + (size_t)r * 128 + ks * 32 + lg * 8);
                } else {
                    bf16x8 z = {0, 0, 0, 0, 0, 0, 0, 0};
                    ahi[rt] = z;
                }
            }
        }
#pragma unroll
        for (int ct = 0; ct < 8; ++ct) {
            size_t boff = (size_t)(((ct * 4 + ks) * 64 + lane) * 8);
            bf16x8 bhi = *(const bf16x8*)(wt_hi + boff);
            bf16x8 blo = *(const bf16x8*)(wt_lo + boff);
            acc[0][ct] = __builtin_amdgcn_mfma_f32_16x16x32_bf16(ahi[0], bhi, acc[0][ct], 0, 0, 0);
            acc[1][ct] = __builtin_amdgcn_mfma_f32_16x16x32_bf16(ahi[1], bhi, acc[1][ct], 0, 0, 0);
            acc[0][ct] = __builtin_amdgcn_mfma_f32_16x16x32_bf16(ahi[0], blo, acc[0][ct], 0, 0, 0);
            acc[1][ct] = __builtin_amdgcn_mfma_f32_16x16x32_bf16(ahi[1], blo, acc[1][ct], 0, 0, 0);
            if (F32A) {
                acc[0][ct] = __builtin_amdgcn_mfma_f32_16x16x32_bf16(alo[0], bhi, acc[0][ct], 0, 0, 0);
                acc[1][ct] = __builtin_amdgcn_mfma_f32_16x16x32_bf16(alo[1], bhi, acc[1][ct], 0, 0, 0);
            }
        }
    }

#pragma unroll
    for (int rt = 0; rt < 2; ++rt) {
#pragma unroll
        for (int reg = 0; reg < 4; ++reg) {
            int row = rowBase + rt * 16 + lg * 4 + reg;
            if (row >= N) continue;
            if (MODE == 0) {
#pragma unroll
                for (int ct = 0; ct < 8; ++ct) {
                    int colc = ct * 16 + l15;
                    float v = acc[rt][ct][reg] + bias[colc];
                    v = v > 0.f ? v : expf(v) - 1.f;
                    out0[(size_t)row * 128 + colc] = f2bf(v);
                }
            } else {
                float dv = dinv[row];
#pragma unroll
                for (int ct = 0; ct < 8; ++ct) {
                    int colc = ct * 16 + l15;
                    out0[(size_t)row * 128 + colc] = f2bf(acc[rt][ct][reg] * dv);
                }
            }
        }
    }
}

// ---------------- gather: h = bf16(elu(dinv[v]*(sum hwb[u] + hwb[v]) + bias)) ----------------
// 16 lanes/node, 16-edge groups (16 row-loads in flight per wave)
__global__ __launch_bounds__(256) void gather_agg(const int* __restrict__ rp,
                                                  const int* __restrict__ csrc,
                                                  const float* __restrict__ dinv,
                                                  const ushort_t* __restrict__ hwb,
                                                  const float* __restrict__ bias,
                                                  ushort_t* __restrict__ h_out) {
    int v = blockIdx.x * 16 + (threadIdx.x >> 4);
    if (v >= NN) return;
    int c8 = (threadIdx.x & 15) << 3;
    int s = rp[v], e = rp[v + 1];
    float acc[8] = {};

    int i = s;
    for (; i + 16 <= e; i += 16) {
        int u[16];
#pragma unroll
        for (int k = 0; k < 16; ++k) u[k] = csrc[i + k];
        ushort8_t r[16];
#pragma unroll
        for (int k = 0; k < 16; ++k) r[k] = *(const ushort8_t*)(hwb + (size_t)u[k] * 128 + c8);
#pragma unroll
        for (int k = 0; k < 16; ++k)
#pragma unroll
            for (int j = 0; j < 8; ++j) acc[j] += bf2f(r[k][j]);
    }
    for (; i + 8 <= e; i += 8) {
        int u[8];
#pragma unroll
        for (int k = 0; k < 8; ++k) u[k] = csrc[i + k];
        ushort8_t r[8];
#pragma unroll
        for (int k = 0; k < 8; ++k) r[k] = *(const ushort8_t*)(hwb + (size_t)u[k] * 128 + c8);
#pragma unroll
        for (int k = 0; k < 8; ++k)
#pragma unroll
            for (int j = 0; j < 8; ++j) acc[j] += bf2f(r[k][j]);
    }
    for (; i < e; ++i) {
        int u = csrc[i];
        ushort8_t r0 = *(const ushort8_t*)(hwb + (size_t)u * 128 + c8);
#pragma unroll
        for (int j = 0; j < 8; ++j) acc[j] += bf2f(r0[j]);
    }

    float di = dinv[v];
    ushort8_t sv = *(const ushort8_t*)(hwb + (size_t)v * 128 + c8);
    ushort8_t o;
#pragma unroll
    for (int j = 0; j < 8; ++j) {
        float t = di * (acc[j] + bf2f(sv[j])) + bias[c8 + j];
        t = t > 0.f ? t : expf(t) - 1.f;
        o[j] = f2bf(t);
    }
    *(ushort8_t*)(h_out + (size_t)v * 128 + c8) = o;
}

// ---------------- readout: 4 blocks/graph, 16 lanes/node (ushort8), LDS reduce ----------------
__global__ __launch_bounds__(256) void readout(const ushort_t* __restrict__ h,
                                               const int* __restrict__ batch,
                                               int n, float* __restrict__ reps) {
    int g = blockIdx.x >> 2;
    int part = blockIdx.x & 3;
    int lo = 0, hi = n;
    while (lo < hi) { int m = (lo + hi) >> 1; if (batch[m] < g) lo = m + 1; else hi = m; }
    int s = lo;
    lo = 0; hi = n;
    while (lo < hi) { int m = (lo + hi) >> 1; if (batch[m] < g + 1) lo = m + 1; else hi = m; }
    int e = lo;

    __shared__ float sh[16][128];
    int ns = threadIdx.x >> 4;          // node slot 0..15
    int L  = threadIdx.x & 15;          // lane within node
    int c8 = L << 3;
    float acc[8] = {};
    // node sequence for this (part, slot): v = s + part + (ns + 16*it)*4
    for (int v = s + part + ns * 4; v < e; v += 64) {
        ushort8_t t = *(const ushort8_t*)(h + (size_t)v * 128 + c8);
#pragma unroll
        for (int j = 0; j < 8; ++j) acc[j] += bf2f(t[j]);
    }
#pragma unroll
    for (int j = 0; j < 8; ++j) sh[ns][c8 + j] = acc[j];
    __syncthreads();
    if (threadIdx.x < 128) {
        int c = threadIdx.x;
        float sum = 0.f;
#pragma unroll
        for (int k = 0; k < 16; ++k) sum += sh[k][c];
        float cnt = (float)(e - s > 0 ? e - s : 1);
        unsafeAtomicAdd(&reps[(size_t)g * 128 + c], sum / cnt);
    }
}

// ---------------- head GEMM (fp32 VALU, tiny) ----------------
__global__ __launch_bounds__(256) void gemm128(const float* __restrict__ A,
                                               const float* __restrict__ W,
                                               const float* __restrict__ bias,
                                               float* __restrict__ out,
                                               int N, int applyElu) {
    __shared__ float xs[64][128];
    __shared__ float ws[128][64];
    const int tid = threadIdx.x;
    const int rowBase = blockIdx.x * 64;
    const int colBase = blockIdx.y * 64;
#pragma unroll
    for (int it = 0; it < 8; ++it) {
        int idx = it * 256 + tid;
        int r = idx >> 5;
        int c4 = (idx & 31) << 2;
        int gr = rowBase + r;
        float4 v = make_float4(0.f, 0.f, 0.f, 0.f);
        if (gr < N) v = *(const float4*)(A + (size_t)gr * 128 + c4);
        *(float4*)(&xs[r][c4]) = v;
    }
#pragma unroll
    for (int it = 0; it < 8; ++it) {
        int idx = it * 256 + tid;
        int k = idx >> 4;
        int c4 = (idx & 15) << 2;
        *(float4*)(&ws[k][c4]) = *(const float4*)(W + (size_t)k * 128 + colBase + c4);
    }
    __syncthreads();
    const int rowg = tid >> 4, colg = tid & 15;
    const int r0 = rowg * 4, c0 = colg * 4;
    float acc[4][4] = {};
#pragma unroll 2
    for (int kb = 0; kb < 128; kb += 4) {
        float4 xr[4], wr[4];
#pragma unroll
        for (int i = 0; i < 4; ++i) xr[i] = *(const float4*)(&xs[r0 + i][kb]);
#pragma unroll
        for (int kk = 0; kk < 4; ++kk) wr[kk] = *(const float4*)(&ws[kb + kk][c0]);
#pragma unroll
        for (int i = 0; i < 4; ++i) {
            const float* xp = (const float*)&xr[i];
#pragma unroll
            for (int kk = 0; kk < 4; ++kk) {
                float xv = xp[kk];
                acc[i][0] = fmaf(xv, wr[kk].x, acc[i][0]);
                acc[i][1] = fmaf(xv, wr[kk].y, acc[i][1]);
                acc[i][2] = fmaf(xv, wr[kk].z, acc[i][2]);
                acc[i][3] = fmaf(xv, wr[kk].w, acc[i][3]);
            }
        }
    }
    float4 b4 = make_float4(0.f, 0.f, 0.f, 0.f);
    if (bias) b4 = *(const float4*)(bias + colBase + c0);
#pragma unroll
    for (int i = 0; i < 4; ++i) {
        int gr = rowBase + r0 + i;
        if (gr < N) {
            float4 o;
            o.x = acc[i][0] + b4.x;
            o.y = acc[i][1] + b4.y;
            o.z = acc[i][2] + b4.z;
            o.w = acc[i][3] + b4.w;
            if (applyElu) {
                o.x = o.x > 0.f ? o.x : expf(o.x) - 1.f;
                o.y = o.y > 0.f ? o.y : expf(o.y) - 1.f;
                o.z = o.z > 0.f ? o.z : expf(o.z) - 1.f;
                o.w = o.w > 0.f ? o.w : expf(o.w) - 1.f;
            }
            *(float4*)(out + (size_t)gr * 128 + colBase + c0) = o;
        }
    }
}

// ---------------- classifier + log_softmax ----------------
__global__ __launch_bounds__(64) void cls_logsoftmax(const float* __restrict__ g,
                                                     const float* __restrict__ cw,
                                                     const float* __restrict__ cb,
                                                     float* __restrict__ out) {
    int r = blockIdx.x;
    __shared__ float row[128];
    __shared__ float lg[10];
    int t = threadIdx.x;
    row[t] = g[(size_t)r * 128 + t];
    row[64 + t] = g[(size_t)r * 128 + 64 + t];
    __syncthreads();
    if (t < 10) {
        float a = cb[t];
        for (int k = 0; k < 128; ++k) a = fmaf(row[k], cw[k * 10 + t], a);
        lg[t] = a;
    }
    __syncthreads();
    if (t == 0) {
        float m = lg[0];
#pragma unroll
        for (int j = 1; j < 10; ++j) m = fmaxf(m, lg[j]);
        float se = 0.f;
#pragma unroll
        for (int j = 0; j < 10; ++j) se += expf(lg[j] - m);
        float L = logf(se);
#pragma unroll
        for (int j = 0; j < 10; ++j) out[(size_t)r * 10 + j] = lg[j] - m - L;
    }
}

extern "C" void kernel_launch(void* const* d_in, const int* in_sizes, int n_in,
                              void* d_out, int out_size, void* d_ws, size_t ws_size,
                              hipStream_t stream) {
    const float* x        = (const float*)d_in[0];
    const float* lin1_w   = (const float*)d_in[1];
    const float* lin1_b   = (const float*)d_in[2];
    const float* gcn_w    = (const float*)d_in[3];
    const float* gcn_b    = (const float*)d_in[4];
    const float* lin_out_w= (const float*)d_in[5];
    const float* lin_out_b= (const float*)d_in[6];
    const float* cls_w    = (const float*)d_in[7];
    const float* cls_b    = (const float*)d_in[8];
    const int*   ei       = (const int*)d_in[9];
    const int*   batch    = (const int*)d_in[10];
    float* out = (float*)d_out;

    const int* erow = ei;
    const int* ecol = ei + NE;

    ushort_t* h     = (ushort_t*)d_ws;                     // NN*128 bf16
    ushort_t* hwb   = h + (size_t)NN * 128;                // NN*128 bf16
    float*    dinv  = (float*)(hwb + (size_t)NN * 128);    // NN
    float*    reps  = dinv + NN;                           // NG*128
    float*    gbuf  = reps + (size_t)NG * 128;             // NG*128
    int*      rp    = (int*)(gbuf + (size_t)NG * 128);     // NN+1
    int*      csrc  = rp + NN + 1;                         // NE
    int*      ghist = csrc + NE;                           // NB
    int*      brp   = ghist + NB;                          // NB+1
    int*      gcur  = brp + NB + 1;                        // NB
    ushort_t* wt_hi = (ushort_t*)(gcur + NB);              // 4*16384
    ushort_t* wt_lo = wt_hi + 4 * 16384;                   // 4*16384
    unsigned int* pairs = (unsigned int*)(wt_lo + 4 * 16384);  // NE

    hipMemsetAsync(ghist, 0, NB * sizeof(int), stream);
    hipMemsetAsync(reps, 0, (size_t)NG * 128 * sizeof(float), stream);

    // ---- CSR build (bucketed) + weight prep ----
    hist_and_prepw<<<512 + 32, 256, 0, stream>>>(ecol, ghist, NE, lin1_w, gcn_w, wt_hi, wt_lo);
    bucket_scan<<<1, NB, 0, stream>>>(ghist, brp, gcur, rp);
    partition_edges<<<(NE + CHUNK - 1) / CHUNK, 256, 0, stream>>>(erow, ecol, gcur, pairs, NE);
    bucket_fill<<<NB, 256, 0, stream>>>(pairs, brp, rp, dinv, csrc);

    const int GEMM_GRID = (NN + 127) / 128;

    // h = bf16(elu(x @ lin1_w + b))
    gemm_mfma<true, 0><<<GEMM_GRID, 256, 0, stream>>>(x, nullptr, wt_hi, wt_lo,
                                                      lin1_b, dinv, h, NN);
    readout<<<NG * 4, 256, 0, stream>>>(h, batch, NN, reps);

    for (int i = 0; i < 3; ++i) {
        gemm_mfma<false, 1><<<GEMM_GRID, 256, 0, stream>>>(nullptr, h,
                                                           wt_hi + (size_t)(i + 1) * 16384,
                                                           wt_lo + (size_t)(i + 1) * 16384,
                                                           nullptr, dinv, hwb, NN);
        gather_agg<<<(NN + 15) / 16, 256, 0, stream>>>(rp, csrc, dinv, hwb,
                                                       gcn_b + (size_t)i * 128, h);
        readout<<<NG * 4, 256, 0, stream>>>(h, batch, NN, reps);
    }

    dim3 gs((NG + 63) / 64, 2);
    gemm128<<<gs, 256, 0, stream>>>(reps, lin_out_w, lin_out_b, gbuf, NG, 1);
    cls_logsoftmax<<<NG, 64, 0, stream>>>(gbuf, cls_w, cls_b, out);
}

// Round 11
// 449.934 us; speedup vs baseline: 1.3245x; 1.0122x over previous
//
#include <hip/hip_runtime.h>
#include <hip/hip_bf16.h>
#include <math.h>

#define NN 100000
#define NE 1600000
#define HID 128
#define NG 512
#define NB 512          // dst buckets
#define RB 196          // nodes per bucket (512*196 = 100352 >= NN)

typedef unsigned short ushort_t;
typedef __attribute__((ext_vector_type(8))) short bf16x8;
typedef __attribute__((ext_vector_type(8))) unsigned short ushort8_t;
typedef __attribute__((ext_vector_type(4))) float f32x4;

__device__ __forceinline__ ushort_t f2bf(float v) {
    unsigned u = __float_as_uint(v);
    unsigned r = (u + 0x7FFF + ((u >> 16) & 1)) >> 16;
    return (ushort_t)r;
}
__device__ __forceinline__ float bf2f(ushort_t u) {
    return __uint_as_float((unsigned)u << 16);
}

// ---------------- bucket histogram (blocks 0..511) + weight prep (blocks 512..543) ----------------
__global__ __launch_bounds__(256) void hist_and_prepw(const int* __restrict__ ecol, int* __restrict__ ghist, int E,
                                                      const float* __restrict__ lin1_w,
                                                      const float* __restrict__ gcn_w,
                                                      ushort_t* __restrict__ wt_hi,
                                                      ushort_t* __restrict__ wt_lo) {
    if (blockIdx.x < 512) {
        __shared__ int lh[NB];
        for (int i = threadIdx.x; i < NB; i += 256) lh[i] = 0;
        __syncthreads();
        for (int e = blockIdx.x * 256 + threadIdx.x; e < E; e += 512 * 256)
            atomicAdd(&lh[ecol[e] / RB], 1);
        __syncthreads();
        for (int i = threadIdx.x; i < NB; i += 256) {
            int c = lh[i];
            if (c) atomicAdd(&ghist[i], c);
        }
    } else {
        int mb = blockIdx.x - 512;
        int m = mb >> 3;
        int chunk = mb & 7;
        const float* W = (m == 0) ? lin1_w : gcn_w + (size_t)(m - 1) * 16384;
        ushort_t* hi = wt_hi + (size_t)m * 16384;
        ushort_t* lo = wt_lo + (size_t)m * 16384;
        for (int i = chunk * 2048 + threadIdx.x; i < (chunk + 1) * 2048; i += 256) {
            int j = i & 7;
            int lane = (i >> 3) & 63;
            int ks = (i >> 9) & 3;
            int ct = (i >> 11) & 7;
            int n = ct * 16 + (lane & 15);
            int k = ks * 32 + (lane >> 4) * 8 + j;
            float v = W[k * 128 + n];
            ushort_t h = f2bf(v);
            hi[i] = h;
            lo[i] = f2bf(v - bf2f(h));
        }
    }
}

// ---------------- scan buckets + per-graph inverse counts ----------------
__global__ __launch_bounds__(NB) void bucket_scan(const int* __restrict__ ghist, int* __restrict__ brp,
                                                  int* __restrict__ gcur, int* __restrict__ rp,
                                                  const int* __restrict__ batch, float* __restrict__ invcnt) {
    __shared__ int s[NB];
    int t = threadIdx.x;
    int v = ghist[t];
    s[t] = v;
    __syncthreads();
    for (int off = 1; off < NB; off <<= 1) {
        int x = (t >= off) ? s[t - off] : 0;
        __syncthreads();
        s[t] += x;
        __syncthreads();
    }
    int ex = s[t] - v;
    brp[t] = ex;
    gcur[t] = ex;
    if (t == NB - 1) { brp[NB] = s[t]; rp[NN] = s[t]; }

    // invcnt[g] = 1 / max(#nodes in graph g, 1)   (t == g; NB == NG)
    int lo = 0, hi = NN;
    while (lo < hi) { int m = (lo + hi) >> 1; if (batch[m] < t) lo = m + 1; else hi = m; }
    int s0 = lo;
    lo = 0; hi = NN;
    while (lo < hi) { int m = (lo + hi) >> 1; if (batch[m] < t + 1) lo = m + 1; else hi = m; }
    int c = lo - s0;
    invcnt[t] = 1.0f / (float)(c > 0 ? c : 1);
}

// ---------------- partition edges into bucket-contiguous packed ints ----------------
// packed = (src << 8) | (dst - bucket*RB)
#define CHUNK 4096
__global__ __launch_bounds__(256) void partition_edges(const int* __restrict__ erow, const int* __restrict__ ecol,
                                                       int* __restrict__ gcur, unsigned int* __restrict__ pairs, int E) {
    __shared__ int cnt[NB];
    __shared__ int base[NB];
    const int t = threadIdx.x;
    const int e0 = blockIdx.x * CHUNK;
    const int e1 = min(e0 + CHUNK, E);
    for (int i = t; i < NB; i += 256) cnt[i] = 0;
    __syncthreads();
    for (int e = e0 + t; e < e1; e += 256) atomicAdd(&cnt[ecol[e] / RB], 1);
    __syncthreads();
    for (int i = t; i < NB; i += 256) {
        int c = cnt[i];
        base[i] = c ? atomicAdd(&gcur[i], c) : 0;
        cnt[i] = 0;
    }
    __syncthreads();
    for (int e = e0 + t; e < e1; e += 256) {
        int d = ecol[e];
        int b = d / RB;
        int off = atomicAdd(&cnt[b], 1);
        pairs[base[b] + off] = ((unsigned)erow[e] << 8) | (unsigned)(d - b * RB);
    }
}

// ---------------- per-bucket: degrees, dinv, rp, fill csrc ----------------
__global__ __launch_bounds__(256) void bucket_fill(const unsigned int* __restrict__ pairs, const int* __restrict__ brp,
                                                   int* __restrict__ rp, float* __restrict__ dinv,
                                                   int* __restrict__ csrc) {
    __shared__ int cnt[RB];
    __shared__ int cur[RB];
    __shared__ int sc[256];
    const int b = blockIdx.x, t = threadIdx.x;
    const int nbase = b * RB;
    const int s = brp[b], e = brp[b + 1];
    for (int i = t; i < RB; i += 256) cnt[i] = 0;
    __syncthreads();
    for (int i = s + t; i < e; i += 256) atomicAdd(&cnt[pairs[i] & 255u], 1);
    __syncthreads();
    int v = (t < RB) ? cnt[t] : 0;
    sc[t] = v;
    __syncthreads();
    for (int off = 1; off < 256; off <<= 1) {
        int x = (t >= off) ? sc[t - off] : 0;
        __syncthreads();
        sc[t] += x;
        __syncthreads();
    }
    if (t < RB) {
        int ex = s + sc[t] - v;
        int node = nbase + t;
        if (node < NN) {
            rp[node] = ex;
            dinv[node] = rsqrtf((float)v + 1.0f);
        }
        cur[t] = ex;
    }
    __syncthreads();
    for (int i = s + t; i < e; i += 256) {
        unsigned int p = pairs[i];
        int slot = atomicAdd(&cur[p & 255u], 1);
        csrc[slot] = (int)(p >> 8);
    }
}

// ---------------- MFMA GEMM ----------------
// F32A=true : A fp32, 3-term split (x @ lin1_w), MODE 0.
// F32A=false: A bf16 exact, 2-term (W hi/lo only), MODE 1.
// MODE 0: out0 = bf16(elu(acc + bias)); MODE 1: out0 = bf16(dinv[row]*acc)
template<bool F32A, int MODE>
__global__ __launch_bounds__(256) void gemm_mfma(const float* __restrict__ A,
                                                 const ushort_t* __restrict__ a_bf,
                                                 const ushort_t* __restrict__ wt_hi,
                                                 const ushort_t* __restrict__ wt_lo,
                                                 const float* __restrict__ bias,
                                                 const float* __restrict__ dinv,
                                                 ushort_t* __restrict__ out0,
                                                 int N) {
    const int lane = threadIdx.x & 63;
    const int wid = threadIdx.x >> 6;
    const int rowBase = blockIdx.x * 128 + wid * 32;
    const int l15 = lane & 15, lg = lane >> 4;

    f32x4 acc[2][8];
#pragma unroll
    for (int rt = 0; rt < 2; ++rt)
#pragma unroll
        for (int ct = 0; ct < 8; ++ct) acc[rt][ct] = (f32x4){0.f, 0.f, 0.f, 0.f};

#pragma unroll
    for (int ks = 0; ks < 4; ++ks) {
        bf16x8 ahi[2], alo[2];
#pragma unroll
        for (int rt = 0; rt < 2; ++rt) {
            int r = rowBase + rt * 16 + l15;
            if (F32A) {
                float av[8];
                if (r < N) {
                    const float* ap = A + (size_t)r * 128 + ks * 32 + lg * 8;
                    float4 a0 = *(const float4*)(ap);
                    float4 a1 = *(const float4*)(ap + 4);
                    av[0] = a0.x; av[1] = a0.y; av[2] = a0.z; av[3] = a0.w;
                    av[4] = a1.x; av[5] = a1.y; av[6] = a1.z; av[7] = a1.w;
                } else {
#pragma unroll
                    for (int j = 0; j < 8; ++j) av[j] = 0.f;
                }
#pragma unroll
                for (int j = 0; j < 8; ++j) {
                    ushort_t h = f2bf(av[j]);
                    ahi[rt][j] = (short)h;
                    alo[rt][j] = (short)f2bf(av[j] - bf2f(h));
                }
            } else {
                if (r < N) {
                    ahi[rt] = *(const bf16x8*)(a_bf + (size_t)r * 128 + ks * 32 + lg * 8);
                } else {
                    bf16x8 z = {0, 0, 0, 0, 0, 0, 0, 0};
                    ahi[rt] = z;
                }
            }
        }
#pragma unroll
        for (int ct = 0; ct < 8; ++ct) {
            size_t boff = (size_t)(((ct * 4 + ks) * 64 + lane) * 8);
            bf16x8 bhi = *(const bf16x8*)(wt_hi + boff);
            bf16x8 blo = *(const bf16x8*)(wt_lo + boff);
            acc[0][ct] = __builtin_amdgcn_mfma_f32_16x16x32_bf16(ahi[0], bhi, acc[0][ct], 0, 0, 0);
            acc[1][ct] = __builtin_amdgcn_mfma_f32_16x16x32_bf16(ahi[1], bhi, acc[1][ct], 0, 0, 0);
            acc[0][ct] = __builtin_amdgcn_mfma_f32_16x16x32_bf16(ahi[0], blo, acc[0][ct], 0, 0, 0);
            acc[1][ct] = __builtin_amdgcn_mfma_f32_16x16x32_bf16(ahi[1], blo, acc[1][ct], 0, 0, 0);
            if (F32A) {
                acc[0][ct] = __builtin_amdgcn_mfma_f32_16x16x32_bf16(alo[0], bhi, acc[0][ct], 0, 0, 0);
                acc[1][ct] = __builtin_amdgcn_mfma_f32_16x16x32_bf16(alo[1], bhi, acc[1][ct], 0, 0, 0);
            }
        }
    }

#pragma unroll
    for (int rt = 0; rt < 2; ++rt) {
#pragma unroll
        for (int reg = 0; reg < 4; ++reg) {
            int row = rowBase + rt * 16 + lg * 4 + reg;
            if (row >= N) continue;
            if (MODE == 0) {
#pragma unroll
                for (int ct = 0; ct < 8; ++ct) {
                    int colc = ct * 16 + l15;
                    float v = acc[rt][ct][reg] + bias[colc];
                    v = v > 0.f ? v : expf(v) - 1.f;
                    out0[(size_t)row * 128 + colc] = f2bf(v);
                }
            } else {
                float dv = dinv[row];
#pragma unroll
                for (int ct = 0; ct < 8; ++ct) {
                    int colc = ct * 16 + l15;
                    out0[(size_t)row * 128 + colc] = f2bf(acc[rt][ct][reg] * dv);
                }
            }
        }
    }
}

// ---------------- gather + fused readout ----------------
// h = bf16(elu(dinv[v]*(sum hwb[u] + hwb[v]) + bias)); also reps[g] += mean contribution.
// 16 lanes/node, 16 nodes/block (6250 blocks exactly cover NN).
__global__ __launch_bounds__(256) void gather_agg(const int* __restrict__ rp,
                                                  const int* __restrict__ csrc,
                                                  const float* __restrict__ dinv,
                                                  const ushort_t* __restrict__ hwb,
                                                  const float* __restrict__ bias,
                                                  const int* __restrict__ batch,
                                                  const float* __restrict__ invcnt,
                                                  float* __restrict__ reps,
                                                  ushort_t* __restrict__ h_out) {
    __shared__ float sh[16][128];
    __shared__ int gid[16];
    const int v0 = blockIdx.x * 16;
    const int ns = (int)(threadIdx.x >> 4);
    int v = v0 + ns;
    int c8 = (int)(threadIdx.x & 15) << 3;
    if (threadIdx.x < 16) {
        int bidx = v0 + (int)threadIdx.x;
        if (bidx > NN - 1) bidx = NN - 1;
        gid[threadIdx.x] = batch[bidx];
    }

    float acc[8] = {};
    if (v < NN) {
        int s = rp[v], e = rp[v + 1];
        int i = s;
        for (; i + 16 <= e; i += 16) {
            int u[16];
#pragma unroll
            for (int k = 0; k < 16; ++k) u[k] = csrc[i + k];
            ushort8_t r[16];
#pragma unroll
            for (int k = 0; k < 16; ++k) r[k] = *(const ushort8_t*)(hwb + (size_t)u[k] * 128 + c8);
#pragma unroll
            for (int k = 0; k < 16; ++k)
#pragma unroll
                for (int j = 0; j < 8; ++j) acc[j] += bf2f(r[k][j]);
        }
        for (; i + 8 <= e; i += 8) {
            int u[8];
#pragma unroll
            for (int k = 0; k < 8; ++k) u[k] = csrc[i + k];
            ushort8_t r[8];
#pragma unroll
            for (int k = 0; k < 8; ++k) r[k] = *(const ushort8_t*)(hwb + (size_t)u[k] * 128 + c8);
#pragma unroll
            for (int k = 0; k < 8; ++k)
#pragma unroll
                for (int j = 0; j < 8; ++j) acc[j] += bf2f(r[k][j]);
        }
        for (; i < e; ++i) {
            int u = csrc[i];
            ushort8_t r0 = *(const ushort8_t*)(hwb + (size_t)u * 128 + c8);
#pragma unroll
            for (int j = 0; j < 8; ++j) acc[j] += bf2f(r0[j]);
        }

        float di = dinv[v];
        ushort8_t sv = *(const ushort8_t*)(hwb + (size_t)v * 128 + c8);
        ushort8_t o;
#pragma unroll
        for (int j = 0; j < 8; ++j) {
            float t = di * (acc[j] + bf2f(sv[j])) + bias[c8 + j];
            t = t > 0.f ? t : expf(t) - 1.f;
            acc[j] = t;                 // keep fp32 for readout
            o[j] = f2bf(t);
        }
        *(ushort8_t*)(h_out + (size_t)v * 128 + c8) = o;
    } else {
#pragma unroll
        for (int j = 0; j < 8; ++j) acc[j] = 0.f;
    }

    // fused readout: per-block segment reduction over the 16 batch-sorted nodes
#pragma unroll
    for (int j = 0; j < 8; ++j) sh[ns][c8 + j] = acc[j];
    __syncthreads();
    if (threadIdx.x < 128) {
        int c = (int)threadIdx.x;
        int nvalid = NN - v0;
        if (nvalid > 16) nvalid = 16;
        float run = sh[0][c];
        int cg = gid[0];
        for (int k = 1; k < nvalid; ++k) {
            int g2 = gid[k];
            if (g2 != cg) {
                unsafeAtomicAdd(&reps[(size_t)cg * 128 + c], run * invcnt[cg]);
                run = 0.f;
                cg = g2;
            }
            run += sh[k][c];
        }
        unsafeAtomicAdd(&reps[(size_t)cg * 128 + c], run * invcnt[cg]);
    }
}

// ---------------- readout (layer 0 only): 4 blocks/graph, ushort8 loads, LDS reduce ----------------
__global__ __launch_bounds__(256) void readout(const ushort_t* __restrict__ h,
                                               const int* __restrict__ batch,
                                               int n, float* __restrict__ reps) {
    int g = blockIdx.x >> 2;
    int part = blockIdx.x & 3;
    int lo = 0, hi = n;
    while (lo < hi) { int m = (lo + hi) >> 1; if (batch[m] < g) lo = m + 1; else hi = m; }
    int s = lo;
    lo = 0; hi = n;
    while (lo < hi) { int m = (lo + hi) >> 1; if (batch[m] < g + 1) lo = m + 1; else hi = m; }
    int e = lo;

    __shared__ float sh[16][128];
    int ns = (int)(threadIdx.x >> 4);
    int L  = (int)(threadIdx.x & 15);
    int c8 = L << 3;
    float acc[8] = {};
    for (int v = s + part + ns * 4; v < e; v += 64) {
        ushort8_t t = *(const ushort8_t*)(h + (size_t)v * 128 + c8);
#pragma unroll
        for (int j = 0; j < 8; ++j) acc[j] += bf2f(t[j]);
    }
#pragma unroll
    for (int j = 0; j < 8; ++j) sh[ns][c8 + j] = acc[j];
    __syncthreads();
    if (threadIdx.x < 128) {
        int c = (int)threadIdx.x;
        float sum = 0.f;
#pragma unroll
        for (int k = 0; k < 16; ++k) sum += sh[k][c];
        float cnt = (float)(e - s > 0 ? e - s : 1);
        unsafeAtomicAdd(&reps[(size_t)g * 128 + c], sum / cnt);
    }
}

// ---------------- head GEMM (fp32 VALU, tiny) ----------------
__global__ __launch_bounds__(256) void gemm128(const float* __restrict__ A,
                                               const float* __restrict__ W,
                                               const float* __restrict__ bias,
                                               float* __restrict__ out,
                                               int N, int applyElu) {
    __shared__ float xs[64][128];
    __shared__ float ws[128][64];
    const int tid = threadIdx.x;
    const int rowBase = blockIdx.x * 64;
    const int colBase = blockIdx.y * 64;
#pragma unroll
    for (int it = 0; it < 8; ++it) {
        int idx = it * 256 + tid;
        int r = idx >> 5;
        int c4 = (idx & 31) << 2;
        int gr = rowBase + r;
        float4 v = make_float4(0.f, 0.f, 0.f, 0.f);
        if (gr < N) v = *(const float4*)(A + (size_t)gr * 128 + c4);
        *(float4*)(&xs[r][c4]) = v;
    }
#pragma unroll
    for (int it = 0; it < 8; ++it) {
        int idx = it * 256 + tid;
        int k = idx >> 4;
        int c4 = (idx & 15) << 2;
        *(float4*)(&ws[k][c4]) = *(const float4*)(W + (size_t)k * 128 + colBase + c4);
    }
    __syncthreads();
    const int rowg = tid >> 4, colg = tid & 15;
    const int r0 = rowg * 4, c0 = colg * 4;
    float acc[4][4] = {};
#pragma unroll 2
    for (int kb = 0; kb < 128; kb += 4) {
        float4 xr[4], wr[4];
#pragma unroll
        for (int i = 0; i < 4; ++i) xr[i] = *(const float4*)(&xs[r0 + i][kb]);
#pragma unroll
        for (int kk = 0; kk < 4; ++kk) wr[kk] = *(const float4*)(&ws[kb + kk][c0]);
#pragma unroll
        for (int i = 0; i < 4; ++i) {
            const float* xp = (const float*)&xr[i];
#pragma unroll
            for (int kk = 0; kk < 4; ++kk) {
                float xv = xp[kk];
                acc[i][0] = fmaf(xv, wr[kk].x, acc[i][0]);
                acc[i][1] = fmaf(xv, wr[kk].y, acc[i][1]);
                acc[i][2] = fmaf(xv, wr[kk].z, acc[i][2]);
                acc[i][3] = fmaf(xv, wr[kk].w, acc[i][3]);
            }
        }
    }
    float4 b4 = make_float4(0.f, 0.f, 0.f, 0.f);
    if (bias) b4 = *(const float4*)(bias + colBase + c0);
#pragma unroll
    for (int i = 0; i < 4; ++i) {
        int gr = rowBase + r0 + i;
        if (gr < N) {
            float4 o;
            o.x = acc[i][0] + b4.x;
            o.y = acc[i][1] + b4.y;
            o.z = acc[i][2] + b4.z;
            o.w = acc[i][3] + b4.w;
            if (applyElu) {
                o.x = o.x > 0.f ? o.x : expf(o.x) - 1.f;
                o.y = o.y > 0.f ? o.y : expf(o.y) - 1.f;
                o.z = o.z > 0.f ? o.z : expf(o.z) - 1.f;
                o.w = o.w > 0.f ? o.w : expf(o.w) - 1.f;
            }
            *(float4*)(out + (size_t)gr * 128 + colBase + c0) = o;
        }
    }
}

// ---------------- classifier + log_softmax ----------------
__global__ __launch_bounds__(64) void cls_logsoftmax(const float* __restrict__ g,
                                                     const float* __restrict__ cw,
                                                     const float* __restrict__ cb,
                                                     float* __restrict__ out) {
    int r = blockIdx.x;
    __shared__ float row[128];
    __shared__ float lg[10];
    int t = threadIdx.x;
    row[t] = g[(size_t)r * 128 + t];
    row[64 + t] = g[(size_t)r * 128 + 64 + t];
    __syncthreads();
    if (t < 10) {
        float a = cb[t];
        for (int k = 0; k < 128; ++k) a = fmaf(row[k], cw[k * 10 + t], a);
        lg[t] = a;
    }
    __syncthreads();
    if (t == 0) {
        float m = lg[0];
#pragma unroll
        for (int j = 1; j < 10; ++j) m = fmaxf(m, lg[j]);
        float se = 0.f;
#pragma unroll
        for (int j = 0; j < 10; ++j) se += expf(lg[j] - m);
        float L = logf(se);
#pragma unroll
        for (int j = 0; j < 10; ++j) out[(size_t)r * 10 + j] = lg[j] - m - L;
    }
}

extern "C" void kernel_launch(void* const* d_in, const int* in_sizes, int n_in,
                              void* d_out, int out_size, void* d_ws, size_t ws_size,
                              hipStream_t stream) {
    const float* x        = (const float*)d_in[0];
    const float* lin1_w   = (const float*)d_in[1];
    const float* lin1_b   = (const float*)d_in[2];
    const float* gcn_w    = (const float*)d_in[3];
    const float* gcn_b    = (const float*)d_in[4];
    const float* lin_out_w= (const float*)d_in[5];
    const float* lin_out_b= (const float*)d_in[6];
    const float* cls_w    = (const float*)d_in[7];
    const float* cls_b    = (const float*)d_in[8];
    const int*   ei       = (const int*)d_in[9];
    const int*   batch    = (const int*)d_in[10];
    float* out = (float*)d_out;

    const int* erow = ei;
    const int* ecol = ei + NE;

    ushort_t* h     = (ushort_t*)d_ws;                     // NN*128 bf16
    ushort_t* hwb   = h + (size_t)NN * 128;                // NN*128 bf16
    float*    dinv  = (float*)(hwb + (size_t)NN * 128);    // NN
    float*    reps  = dinv + NN;                           // NG*128
    float*    gbuf  = reps + (size_t)NG * 128;             // NG*128
    float*    invcnt= gbuf + (size_t)NG * 128;             // NG
    int*      rp    = (int*)(invcnt + NG);                 // NN+1
    int*      csrc  = rp + NN + 1;                         // NE
    int*      ghist = csrc + NE;                           // NB
    int*      brp   = ghist + NB;                          // NB+1
    int*      gcur  = brp + NB + 1;                        // NB
    ushort_t* wt_hi = (ushort_t*)(gcur + NB);              // 4*16384
    ushort_t* wt_lo = wt_hi + 4 * 16384;                   // 4*16384
    unsigned int* pairs = (unsigned int*)(wt_lo + 4 * 16384);  // NE

    hipMemsetAsync(ghist, 0, NB * sizeof(int), stream);
    hipMemsetAsync(reps, 0, (size_t)NG * 128 * sizeof(float), stream);

    // ---- CSR build (bucketed) + weight prep + invcnt ----
    hist_and_prepw<<<512 + 32, 256, 0, stream>>>(ecol, ghist, NE, lin1_w, gcn_w, wt_hi, wt_lo);
    bucket_scan<<<1, NB, 0, stream>>>(ghist, brp, gcur, rp, batch, invcnt);
    partition_edges<<<(NE + CHUNK - 1) / CHUNK, 256, 0, stream>>>(erow, ecol, gcur, pairs, NE);
    bucket_fill<<<NB, 256, 0, stream>>>(pairs, brp, rp, dinv, csrc);

    const int GEMM_GRID = (NN + 127) / 128;

    // h = bf16(elu(x @ lin1_w + b))
    gemm_mfma<true, 0><<<GEMM_GRID, 256, 0, stream>>>(x, nullptr, wt_hi, wt_lo,
                                                      lin1_b, dinv, h, NN);
    readout<<<NG * 4, 256, 0, stream>>>(h, batch, NN, reps);

    for (int i = 0; i < 3; ++i) {
        gemm_mfma<false, 1><<<GEMM_GRID, 256, 0, stream>>>(nullptr, h,
                                                           wt_hi + (size_t)(i + 1) * 16384,
                                                           wt_lo + (size_t)(i + 1) * 16384,
                                                           nullptr, dinv, hwb, NN);
        gather_agg<<<(NN + 15) / 16, 256, 0, stream>>>(rp, csrc, dinv, hwb,
                                                       gcn_b + (size_t)i * 128,
                                                       batch, invcnt, reps, h);
    }

    dim3 gs((NG + 63) / 64, 2);
    gemm128<<<gs, 256, 0, stream>>>(reps, lin_out_w, lin_out_b, gbuf, NG, 1);
    cls_logsoftmax<<<NG, 64, 0, stream>>>(gbuf, cls_w, cls_b, out);
}

// Round 12
// 434.162 us; speedup vs baseline: 1.3726x; 1.0363x over previous
//
#include <hip/hip_runtime.h>
#include <hip/hip_bf16.h>
#include <math.h>

#define NN 100000
#define NE 1600000
#define HID 128
#define NG 512
#define NB 512          // dst buckets
#define RB 196          // nodes per bucket (512*196 = 100352 >= NN)
#define CHUNK 4096
#define NPART ((NE + CHUNK - 1) / CHUNK)   // 391
#define GEMM_GRID ((NN + 127) / 128)       // 782

typedef unsigned short ushort_t;
typedef __attribute__((ext_vector_type(8))) short bf16x8;
typedef __attribute__((ext_vector_type(8))) unsigned short ushort8_t;
typedef __attribute__((ext_vector_type(4))) float f32x4;

__device__ __forceinline__ ushort_t f2bf(float v) {
    unsigned u = __float_as_uint(v);
    unsigned r = (u + 0x7FFF + ((u >> 16) & 1)) >> 16;
    return (ushort_t)r;
}
__device__ __forceinline__ float bf2f(ushort_t u) {
    return __uint_as_float((unsigned)u << 16);
}

// PERM layout for h: node v, col k -> (v>>4)*2048 + (k>>3)*128 + (v&15)*8 + (k&7)

// ---------------- bucket histogram (blocks 0..511) + weight prep (blocks 512..543) ----------------
__global__ __launch_bounds__(256) void hist_and_prepw(const int* __restrict__ ecol, int* __restrict__ ghist, int E,
                                                      const float* __restrict__ lin1_w,
                                                      const float* __restrict__ gcn_w,
                                                      ushort_t* __restrict__ wt_hi,
                                                      ushort_t* __restrict__ wt_lo) {
    if (blockIdx.x < 512) {
        __shared__ int lh[NB];
        for (int i = threadIdx.x; i < NB; i += 256) lh[i] = 0;
        __syncthreads();
        for (int e = blockIdx.x * 256 + threadIdx.x; e < E; e += 512 * 256)
            atomicAdd(&lh[ecol[e] / RB], 1);
        __syncthreads();
        for (int i = threadIdx.x; i < NB; i += 256) {
            int c = lh[i];
            if (c) atomicAdd(&ghist[i], c);
        }
    } else {
        int mb = blockIdx.x - 512;
        int m = mb >> 3;
        int chunk = mb & 7;
        const float* W = (m == 0) ? lin1_w : gcn_w + (size_t)(m - 1) * 16384;
        ushort_t* hi = wt_hi + (size_t)m * 16384;
        ushort_t* lo = wt_lo + (size_t)m * 16384;
        for (int i = chunk * 2048 + threadIdx.x; i < (chunk + 1) * 2048; i += 256) {
            int j = i & 7;
            int lane = (i >> 3) & 63;
            int ks = (i >> 9) & 3;
            int ct = (i >> 11) & 7;
            int n = ct * 16 + (lane & 15);
            int k = ks * 32 + (lane >> 4) * 8 + j;
            float v = W[k * 128 + n];
            ushort_t h = f2bf(v);
            hi[i] = h;
            lo[i] = f2bf(v - bf2f(h));
        }
    }
}

// ---------------- scan buckets + per-graph inverse counts ----------------
__global__ __launch_bounds__(NB) void bucket_scan(const int* __restrict__ ghist, int* __restrict__ brp,
                                                  int* __restrict__ gcur, int* __restrict__ rp,
                                                  const int* __restrict__ batch, float* __restrict__ invcnt) {
    __shared__ int s[NB];
    int t = threadIdx.x;
    int v = ghist[t];
    s[t] = v;
    __syncthreads();
    for (int off = 1; off < NB; off <<= 1) {
        int x = (t >= off) ? s[t - off] : 0;
        __syncthreads();
        s[t] += x;
        __syncthreads();
    }
    int ex = s[t] - v;
    brp[t] = ex;
    gcur[t] = ex;
    if (t == NB - 1) { brp[NB] = s[t]; rp[NN] = s[t]; }

    int lo = 0, hi = NN;
    while (lo < hi) { int m = (lo + hi) >> 1; if (batch[m] < t) lo = m + 1; else hi = m; }
    int s0 = lo;
    lo = 0; hi = NN;
    while (lo < hi) { int m = (lo + hi) >> 1; if (batch[m] < t + 1) lo = m + 1; else hi = m; }
    int c = lo - s0;
    invcnt[t] = 1.0f / (float)(c > 0 ? c : 1);
}

// ---------------- GEMM body (shared device code) ----------------
// F32A=true : A fp32 row-major, 3-term split, MODE 0 (out0 = PERM h = bf16(elu(acc+bias)))
// F32A=false: A bf16 PERM layout, 2-term,      MODE 1 (out0 = row-major hwb = bf16(dinv*acc))
template<bool F32A, int MODE>
__device__ __forceinline__ void gemm_body(int bid, int tid,
                                          const float* __restrict__ A,
                                          const ushort_t* __restrict__ a_bf,
                                          const ushort_t* __restrict__ wt_hi,
                                          const ushort_t* __restrict__ wt_lo,
                                          const float* __restrict__ bias,
                                          const float* __restrict__ dinv,
                                          ushort_t* __restrict__ out0,
                                          int N) {
    const int lane = tid & 63;
    const int wid = tid >> 6;
    const int rowBase = bid * 128 + wid * 32;
    const int rblk = rowBase >> 4;
    const int l15 = lane & 15, lg = lane >> 4;

    f32x4 acc[2][8];
#pragma unroll
    for (int rt = 0; rt < 2; ++rt)
#pragma unroll
        for (int ct = 0; ct < 8; ++ct) acc[rt][ct] = (f32x4){0.f, 0.f, 0.f, 0.f};

#pragma unroll
    for (int ks = 0; ks < 4; ++ks) {
        bf16x8 ahi[2], alo[2];
#pragma unroll
        for (int rt = 0; rt < 2; ++rt) {
            int r = rowBase + rt * 16 + l15;
            if (F32A) {
                float av[8];
                if (r < N) {
                    const float* ap = A + (size_t)r * 128 + ks * 32 + lg * 8;
                    float4 a0 = *(const float4*)(ap);
                    float4 a1 = *(const float4*)(ap + 4);
                    av[0] = a0.x; av[1] = a0.y; av[2] = a0.z; av[3] = a0.w;
                    av[4] = a1.x; av[5] = a1.y; av[6] = a1.z; av[7] = a1.w;
                } else {
#pragma unroll
                    for (int j = 0; j < 8; ++j) av[j] = 0.f;
                }
#pragma unroll
                for (int j = 0; j < 8; ++j) {
                    ushort_t h = f2bf(av[j]);
                    ahi[rt][j] = (short)h;
                    alo[rt][j] = (short)f2bf(av[j] - bf2f(h));
                }
            } else {
                if (r < N) {
                    // PERM: coalesced 1KB wave-load
                    ahi[rt] = *(const bf16x8*)(a_bf + (size_t)(rblk + rt) * 2048 + (ks * 4 + lg) * 128 + l15 * 8);
                } else {
                    bf16x8 z = {0, 0, 0, 0, 0, 0, 0, 0};
                    ahi[rt] = z;
                }
            }
        }
#pragma unroll
        for (int ct = 0; ct < 8; ++ct) {
            size_t boff = (size_t)(((ct * 4 + ks) * 64 + lane) * 8);
            bf16x8 bhi = *(const bf16x8*)(wt_hi + boff);
            bf16x8 blo = *(const bf16x8*)(wt_lo + boff);
            acc[0][ct] = __builtin_amdgcn_mfma_f32_16x16x32_bf16(ahi[0], bhi, acc[0][ct], 0, 0, 0);
            acc[1][ct] = __builtin_amdgcn_mfma_f32_16x16x32_bf16(ahi[1], bhi, acc[1][ct], 0, 0, 0);
            acc[0][ct] = __builtin_amdgcn_mfma_f32_16x16x32_bf16(ahi[0], blo, acc[0][ct], 0, 0, 0);
            acc[1][ct] = __builtin_amdgcn_mfma_f32_16x16x32_bf16(ahi[1], blo, acc[1][ct], 0, 0, 0);
            if (F32A) {
                acc[0][ct] = __builtin_amdgcn_mfma_f32_16x16x32_bf16(alo[0], bhi, acc[0][ct], 0, 0, 0);
                acc[1][ct] = __builtin_amdgcn_mfma_f32_16x16x32_bf16(alo[1], bhi, acc[1][ct], 0, 0, 0);
            }
        }
    }

#pragma unroll
    for (int rt = 0; rt < 2; ++rt) {
#pragma unroll
        for (int reg = 0; reg < 4; ++reg) {
            int row = rowBase + rt * 16 + lg * 4 + reg;
            if (row >= N) continue;
            if (MODE == 0) {
                int r16 = lg * 4 + reg;
#pragma unroll
                for (int ct = 0; ct < 8; ++ct) {
                    int colc = ct * 16 + l15;
                    float v = acc[rt][ct][reg] + bias[colc];
                    v = v > 0.f ? v : expf(v) - 1.f;
                    // PERM write
                    out0[(size_t)(rblk + rt) * 2048 + (colc >> 3) * 128 + r16 * 8 + (colc & 7)] = f2bf(v);
                }
            } else {
                float dv = dinv[row];
#pragma unroll
                for (int ct = 0; ct < 8; ++ct) {
                    int colc = ct * 16 + l15;
                    out0[(size_t)row * 128 + colc] = f2bf(acc[rt][ct][reg] * dv);
                }
            }
        }
    }
}

// ---------------- fused: partition (blocks 0..NPART-1) + gemm1 (blocks NPART..) ----------------
__global__ __launch_bounds__(256) void part_gemm1(const int* __restrict__ erow, const int* __restrict__ ecol,
                                                  int* __restrict__ gcur, unsigned int* __restrict__ pairs, int E,
                                                  const float* __restrict__ x,
                                                  const ushort_t* __restrict__ wt_hi,
                                                  const ushort_t* __restrict__ wt_lo,
                                                  const float* __restrict__ lin1_b,
                                                  ushort_t* __restrict__ h) {
    if (blockIdx.x < NPART) {
        __shared__ int cnt[NB];
        __shared__ int base[NB];
        const int t = threadIdx.x;
        const int e0 = blockIdx.x * CHUNK;
        const int e1 = min(e0 + CHUNK, E);
        for (int i = t; i < NB; i += 256) cnt[i] = 0;
        __syncthreads();
        for (int e = e0 + t; e < e1; e += 256) atomicAdd(&cnt[ecol[e] / RB], 1);
        __syncthreads();
        for (int i = t; i < NB; i += 256) {
            int c = cnt[i];
            base[i] = c ? atomicAdd(&gcur[i], c) : 0;
            cnt[i] = 0;
        }
        __syncthreads();
        for (int e = e0 + t; e < e1; e += 256) {
            int d = ecol[e];
            int b = d / RB;
            int off = atomicAdd(&cnt[b], 1);
            pairs[base[b] + off] = ((unsigned)erow[e] << 8) | (unsigned)(d - b * RB);
        }
    } else {
        gemm_body<true, 0>(blockIdx.x - NPART, threadIdx.x, x, nullptr, wt_hi, wt_lo,
                           lin1_b, nullptr, h, NN);
    }
}

// ---------------- fused: bucket_fill (blocks 0..511) + readout0 (blocks 512..2559) ----------------
__global__ __launch_bounds__(256) void fill_readout0(const unsigned int* __restrict__ pairs, const int* __restrict__ brp,
                                                     int* __restrict__ rp, float* __restrict__ dinv,
                                                     int* __restrict__ csrc,
                                                     const ushort_t* __restrict__ h,
                                                     const int* __restrict__ batch,
                                                     const float* __restrict__ invcnt,
                                                     float* __restrict__ reps) {
    if (blockIdx.x < NB) {
        __shared__ int cnt[RB];
        __shared__ int cur[RB];
        __shared__ int sc[256];
        const int b = blockIdx.x, t = threadIdx.x;
        const int nbase = b * RB;
        const int s = brp[b], e = brp[b + 1];
        for (int i = t; i < RB; i += 256) cnt[i] = 0;
        __syncthreads();
        for (int i = s + t; i < e; i += 256) atomicAdd(&cnt[pairs[i] & 255u], 1);
        __syncthreads();
        int v = (t < RB) ? cnt[t] : 0;
        sc[t] = v;
        __syncthreads();
        for (int off = 1; off < 256; off <<= 1) {
            int x = (t >= off) ? sc[t - off] : 0;
            __syncthreads();
            sc[t] += x;
            __syncthreads();
        }
        if (t < RB) {
            int ex = s + sc[t] - v;
            int node = nbase + t;
            if (node < NN) {
                rp[node] = ex;
                dinv[node] = rsqrtf((float)v + 1.0f);
            }
            cur[t] = ex;
        }
        __syncthreads();
        for (int i = s + t; i < e; i += 256) {
            unsigned int p = pairs[i];
            int slot = atomicAdd(&cur[p & 255u], 1);
            csrc[slot] = (int)(p >> 8);
        }
    } else {
        // readout0 over PERM h
        int bb = blockIdx.x - NB;
        int g = bb >> 2;
        int part = bb & 3;
        int lo = 0, hi = NN;
        while (lo < hi) { int m = (lo + hi) >> 1; if (batch[m] < g) lo = m + 1; else hi = m; }
        int s = lo;
        lo = 0; hi = NN;
        while (lo < hi) { int m = (lo + hi) >> 1; if (batch[m] < g + 1) lo = m + 1; else hi = m; }
        int e = lo;

        __shared__ float sh[16][136];
        int ns = (int)(threadIdx.x >> 4);
        int L  = (int)(threadIdx.x & 15);
        int c8 = L << 3;
        float acc[8] = {};
        for (int v = s + part + ns * 4; v < e; v += 64) {
            ushort8_t t = *(const ushort8_t*)(h + (size_t)(v >> 4) * 2048 + L * 128 + (v & 15) * 8);
#pragma unroll
            for (int j = 0; j < 8; ++j) acc[j] += bf2f(t[j]);
        }
#pragma unroll
        for (int j = 0; j < 8; ++j) sh[ns][c8 + j] = acc[j];
        __syncthreads();
        if (threadIdx.x < 128) {
            int c = (int)threadIdx.x;
            float sum = 0.f;
#pragma unroll
            for (int k = 0; k < 16; ++k) sum += sh[k][c];
            unsafeAtomicAdd(&reps[(size_t)g * 128 + c], sum * invcnt[g]);
        }
    }
}

// ---------------- standalone GCN gemm (MODE 1) ----------------
__global__ __launch_bounds__(256) void gemm_gcn(const ushort_t* __restrict__ a_bf,
                                                const ushort_t* __restrict__ wt_hi,
                                                const ushort_t* __restrict__ wt_lo,
                                                const float* __restrict__ dinv,
                                                ushort_t* __restrict__ hwb) {
    gemm_body<false, 1>(blockIdx.x, threadIdx.x, nullptr, a_bf, wt_hi, wt_lo,
                        nullptr, dinv, hwb, NN);
}

// ---------------- gather + fused readout; h written in PERM layout ----------------
__global__ __launch_bounds__(256) void gather_agg(const int* __restrict__ rp,
                                                  const int* __restrict__ csrc,
                                                  const float* __restrict__ dinv,
                                                  const ushort_t* __restrict__ hwb,
                                                  const float* __restrict__ bias,
                                                  const int* __restrict__ batch,
                                                  const float* __restrict__ invcnt,
                                                  float* __restrict__ reps,
                                                  ushort_t* __restrict__ h_out) {
    __shared__ float sh[16][136];
    __shared__ int gid[16];
    const int v0 = blockIdx.x * 16;
    const int ns = (int)(threadIdx.x >> 4);
    int v = v0 + ns;
    int L = (int)(threadIdx.x & 15);
    int c8 = L << 3;
    if (threadIdx.x < 16) {
        int bidx = v0 + (int)threadIdx.x;
        if (bidx > NN - 1) bidx = NN - 1;
        gid[threadIdx.x] = batch[bidx];
    }

    float acc[8] = {};
    if (v < NN) {
        int s = rp[v], e = rp[v + 1];
        int i = s;
        for (; i + 16 <= e; i += 16) {
            int u[16];
#pragma unroll
            for (int k = 0; k < 16; ++k) u[k] = csrc[i + k];
            ushort8_t r[16];
#pragma unroll
            for (int k = 0; k < 16; ++k) r[k] = *(const ushort8_t*)(hwb + (size_t)u[k] * 128 + c8);
#pragma unroll
            for (int k = 0; k < 16; ++k)
#pragma unroll
                for (int j = 0; j < 8; ++j) acc[j] += bf2f(r[k][j]);
        }
        for (; i + 8 <= e; i += 8) {
            int u[8];
#pragma unroll
            for (int k = 0; k < 8; ++k) u[k] = csrc[i + k];
            ushort8_t r[8];
#pragma unroll
            for (int k = 0; k < 8; ++k) r[k] = *(const ushort8_t*)(hwb + (size_t)u[k] * 128 + c8);
#pragma unroll
            for (int k = 0; k < 8; ++k)
#pragma unroll
                for (int j = 0; j < 8; ++j) acc[j] += bf2f(r[k][j]);
        }
        for (; i < e; ++i) {
            int u = csrc[i];
            ushort8_t r0 = *(const ushort8_t*)(hwb + (size_t)u * 128 + c8);
#pragma unroll
            for (int j = 0; j < 8; ++j) acc[j] += bf2f(r0[j]);
        }

        float di = dinv[v];
        ushort8_t sv = *(const ushort8_t*)(hwb + (size_t)v * 128 + c8);
        ushort8_t o;
#pragma unroll
        for (int j = 0; j < 8; ++j) {
            float t = di * (acc[j] + bf2f(sv[j])) + bias[c8 + j];
            t = t > 0.f ? t : expf(t) - 1.f;
            acc[j] = t;
            o[j] = f2bf(t);
        }
        // PERM write: rb = blockIdx.x, frag = L, slot = ns
        *(ushort8_t*)(h_out + (size_t)blockIdx.x * 2048 + L * 128 + ns * 8) = o;
    } else {
#pragma unroll
        for (int j = 0; j < 8; ++j) acc[j] = 0.f;
    }

    // fused readout: per-block segment reduction over the 16 batch-sorted nodes
#pragma unroll
    for (int j = 0; j < 8; ++j) sh[ns][c8 + j] = acc[j];
    __syncthreads();
    if (threadIdx.x < 128) {
        int c = (int)threadIdx.x;
        int nvalid = NN - v0;
        if (nvalid > 16) nvalid = 16;
        float run = sh[0][c];
        int cg = gid[0];
        for (int k = 1; k < nvalid; ++k) {
            int g2 = gid[k];
            if (g2 != cg) {
                unsafeAtomicAdd(&reps[(size_t)cg * 128 + c], run * invcnt[cg]);
                run = 0.f;
                cg = g2;
            }
            run += sh[k][c];
        }
        unsafeAtomicAdd(&reps[(size_t)cg * 128 + c], run * invcnt[cg]);
    }
}

// ---------------- fused head: g=elu(reps@Wout+b); logits=g@cls+b; log_softmax ----------------
__global__ __launch_bounds__(128) void head_fused(const float* __restrict__ reps,
                                                  const float* __restrict__ wout,
                                                  const float* __restrict__ bout,
                                                  const float* __restrict__ cw,
                                                  const float* __restrict__ cb,
                                                  float* __restrict__ out) {
    __shared__ float rrow[128];
    __shared__ float gg[128];
    __shared__ float lg[10];
    int t = threadIdx.x;
    int g = blockIdx.x;
    rrow[t] = reps[(size_t)g * 128 + t];
    __syncthreads();
    float a = bout[t];
    for (int k = 0; k < 128; ++k) a = fmaf(rrow[k], wout[k * 128 + t], a);
    a = a > 0.f ? a : expf(a) - 1.f;
    gg[t] = a;
    __syncthreads();
    if (t < 10) {
        float s = cb[t];
        for (int k = 0; k < 128; ++k) s = fmaf(gg[k], cw[k * 10 + t], s);
        lg[t] = s;
    }
    __syncthreads();
    if (t == 0) {
        float m = lg[0];
#pragma unroll
        for (int j = 1; j < 10; ++j) m = fmaxf(m, lg[j]);
        float se = 0.f;
#pragma unroll
        for (int j = 0; j < 10; ++j) se += expf(lg[j] - m);
        float L = logf(se);
#pragma unroll
        for (int j = 0; j < 10; ++j) out[(size_t)g * 10 + j] = lg[j] - m - L;
    }
}

extern "C" void kernel_launch(void* const* d_in, const int* in_sizes, int n_in,
                              void* d_out, int out_size, void* d_ws, size_t ws_size,
                              hipStream_t stream) {
    const float* x        = (const float*)d_in[0];
    const float* lin1_w   = (const float*)d_in[1];
    const float* lin1_b   = (const float*)d_in[2];
    const float* gcn_w    = (const float*)d_in[3];
    const float* gcn_b    = (const float*)d_in[4];
    const float* lin_out_w= (const float*)d_in[5];
    const float* lin_out_b= (const float*)d_in[6];
    const float* cls_w    = (const float*)d_in[7];
    const float* cls_b    = (const float*)d_in[8];
    const int*   ei       = (const int*)d_in[9];
    const int*   batch    = (const int*)d_in[10];
    float* out = (float*)d_out;

    const int* erow = ei;
    const int* ecol = ei + NE;

    ushort_t* h     = (ushort_t*)d_ws;                     // NN*128 bf16 (PERM layout)
    ushort_t* hwb   = h + (size_t)NN * 128;                // NN*128 bf16 (row-major)
    float*    dinv  = (float*)(hwb + (size_t)NN * 128);    // NN
    float*    reps  = dinv + NN;                           // NG*128
    float*    invcnt= reps + (size_t)NG * 128;             // NG
    int*      rp    = (int*)(invcnt + NG);                 // NN+1
    int*      csrc  = rp + NN + 1;                         // NE
    int*      ghist = csrc + NE;                           // NB
    int*      brp   = ghist + NB;                          // NB+1
    int*      gcur  = brp + NB + 1;                        // NB
    ushort_t* wt_hi = (ushort_t*)(gcur + NB);              // 4*16384
    ushort_t* wt_lo = wt_hi + 4 * 16384;                   // 4*16384
    unsigned int* pairs = (unsigned int*)(wt_lo + 4 * 16384);  // NE

    hipMemsetAsync(ghist, 0, NB * sizeof(int), stream);
    hipMemsetAsync(reps, 0, (size_t)NG * 128 * sizeof(float), stream);

    // CSR build + weight prep + first GEMM, launch-fused where independent
    hist_and_prepw<<<512 + 32, 256, 0, stream>>>(ecol, ghist, NE, lin1_w, gcn_w, wt_hi, wt_lo);
    bucket_scan<<<1, NB, 0, stream>>>(ghist, brp, gcur, rp, batch, invcnt);
    part_gemm1<<<NPART + GEMM_GRID, 256, 0, stream>>>(erow, ecol, gcur, pairs, NE,
                                                      x, wt_hi, wt_lo, lin1_b, h);
    fill_readout0<<<NB + NG * 4, 256, 0, stream>>>(pairs, brp, rp, dinv, csrc,
                                                   h, batch, invcnt, reps);

    for (int i = 0; i < 3; ++i) {
        gemm_gcn<<<GEMM_GRID, 256, 0, stream>>>(h, wt_hi + (size_t)(i + 1) * 16384,
                                                wt_lo + (size_t)(i + 1) * 16384,
                                                dinv, hwb);
        gather_agg<<<(NN + 15) / 16, 256, 0, stream>>>(rp, csrc, dinv, hwb,
                                                       gcn_b + (size_t)i * 128,
                                                       batch, invcnt, reps, h);
    }

    head_fused<<<NG, 128, 0, stream>>>(reps, lin_out_w, lin_out_b, cls_w, cls_b, out);
}

// Round 13
// 427.143 us; speedup vs baseline: 1.3952x; 1.0164x over previous
//
#include <hip/hip_runtime.h>
#include <hip/hip_bf16.h>
#include <math.h>

#define NN 100000
#define NE 1600000
#define HID 128
#define NG 512
#define NB 512          // dst buckets
#define RB 196          // nodes per bucket (512*196 = 100352 >= NN)
#define PCHUNK 16384
#define NPARTB ((NE + PCHUNK - 1) / PCHUNK)   // 98
#define GEMM_GRID ((NN + 127) / 128)          // 782

typedef unsigned short ushort_t;
typedef __attribute__((ext_vector_type(8))) short bf16x8;
typedef __attribute__((ext_vector_type(8))) unsigned short ushort8_t;
typedef __attribute__((ext_vector_type(4))) float f32x4;

__device__ __forceinline__ ushort_t f2bf(float v) {
    unsigned u = __float_as_uint(v);
    unsigned r = (u + 0x7FFF + ((u >> 16) & 1)) >> 16;
    return (ushort_t)r;
}
__device__ __forceinline__ float bf2f(ushort_t u) {
    return __uint_as_float((unsigned)u << 16);
}

// PERM layout for h: node v, col k -> (v>>4)*2048 + (k>>3)*128 + (v&15)*8 + (k&7)

// ---------------- K1: per-block bucket histogram (no global atomics) + weight prep ----------------
__global__ __launch_bounds__(256) void hist_prepw(const int* __restrict__ ecol, int* __restrict__ bcount,
                                                  const float* __restrict__ lin1_w,
                                                  const float* __restrict__ gcn_w,
                                                  ushort_t* __restrict__ wt_hi,
                                                  ushort_t* __restrict__ wt_lo) {
    if (blockIdx.x < NPARTB) {
        __shared__ int lh[NB];
        const int blk = blockIdx.x, t = threadIdx.x;
        for (int i = t; i < NB; i += 256) lh[i] = 0;
        __syncthreads();
        const int e0 = blk * PCHUNK;
        const int e1 = min(e0 + PCHUNK, NE);
        for (int e = e0 + t; e < e1; e += 256) atomicAdd(&lh[ecol[e] / RB], 1);
        __syncthreads();
        for (int i = t; i < NB; i += 256) bcount[blk * NB + i] = lh[i];
    } else {
        int mb = blockIdx.x - NPARTB;
        int m = mb >> 3;
        int chunk = mb & 7;
        const float* W = (m == 0) ? lin1_w : gcn_w + (size_t)(m - 1) * 16384;
        ushort_t* hi = wt_hi + (size_t)m * 16384;
        ushort_t* lo = wt_lo + (size_t)m * 16384;
        for (int i = chunk * 2048 + threadIdx.x; i < (chunk + 1) * 2048; i += 256) {
            int j = i & 7;
            int lane = (i >> 3) & 63;
            int ks = (i >> 9) & 3;
            int ct = (i >> 11) & 7;
            int n = ct * 16 + (lane & 15);
            int k = ks * 32 + (lane >> 4) * 8 + j;
            float v = W[k * 128 + n];
            ushort_t h = f2bf(v);
            hi[i] = h;
            lo[i] = f2bf(v - bf2f(h));
        }
    }
}

// ---------------- K2: per-bucket block bases + bucket scan + invcnt (1 block, NB threads) ----------------
__global__ __launch_bounds__(NB) void scan_bases(const int* __restrict__ bcount, int* __restrict__ basew,
                                                 int* __restrict__ brp, int* __restrict__ rp,
                                                 const int* __restrict__ batch, float* __restrict__ invcnt) {
    __shared__ int s[NB];
    int t = threadIdx.x;
    int tot = 0;
    for (int k = 0; k < NPARTB; ++k) {
        int c = bcount[k * NB + t];
        basew[k * NB + t] = tot;     // within-bucket offset of block k
        tot += c;
    }
    s[t] = tot;
    __syncthreads();
    for (int off = 1; off < NB; off <<= 1) {
        int x = (t >= off) ? s[t - off] : 0;
        __syncthreads();
        s[t] += x;
        __syncthreads();
    }
    int ex = s[t] - tot;
    brp[t] = ex;
    if (t == NB - 1) { brp[NB] = s[t]; rp[NN] = s[t]; }

    int lo = 0, hi = NN;
    while (lo < hi) { int m = (lo + hi) >> 1; if (batch[m] < t) lo = m + 1; else hi = m; }
    int s0 = lo;
    lo = 0; hi = NN;
    while (lo < hi) { int m = (lo + hi) >> 1; if (batch[m] < t + 1) lo = m + 1; else hi = m; }
    int c = lo - s0;
    invcnt[t] = 1.0f / (float)(c > 0 ? c : 1);
}

// ---------------- GEMM body (shared device code) ----------------
template<bool F32A, int MODE>
__device__ __forceinline__ void gemm_body(int bid, int tid,
                                          const float* __restrict__ A,
                                          const ushort_t* __restrict__ a_bf,
                                          const ushort_t* __restrict__ wt_hi,
                                          const ushort_t* __restrict__ wt_lo,
                                          const float* __restrict__ bias,
                                          const float* __restrict__ dinv,
                                          ushort_t* __restrict__ out0,
                                          int N) {
    const int lane = tid & 63;
    const int wid = tid >> 6;
    const int rowBase = bid * 128 + wid * 32;
    const int rblk = rowBase >> 4;
    const int l15 = lane & 15, lg = lane >> 4;

    f32x4 acc[2][8];
#pragma unroll
    for (int rt = 0; rt < 2; ++rt)
#pragma unroll
        for (int ct = 0; ct < 8; ++ct) acc[rt][ct] = (f32x4){0.f, 0.f, 0.f, 0.f};

#pragma unroll
    for (int ks = 0; ks < 4; ++ks) {
        bf16x8 ahi[2], alo[2];
#pragma unroll
        for (int rt = 0; rt < 2; ++rt) {
            int r = rowBase + rt * 16 + l15;
            if (F32A) {
                float av[8];
                if (r < N) {
                    const float* ap = A + (size_t)r * 128 + ks * 32 + lg * 8;
                    float4 a0 = *(const float4*)(ap);
                    float4 a1 = *(const float4*)(ap + 4);
                    av[0] = a0.x; av[1] = a0.y; av[2] = a0.z; av[3] = a0.w;
                    av[4] = a1.x; av[5] = a1.y; av[6] = a1.z; av[7] = a1.w;
                } else {
#pragma unroll
                    for (int j = 0; j < 8; ++j) av[j] = 0.f;
                }
#pragma unroll
                for (int j = 0; j < 8; ++j) {
                    ushort_t h = f2bf(av[j]);
                    ahi[rt][j] = (short)h;
                    alo[rt][j] = (short)f2bf(av[j] - bf2f(h));
                }
            } else {
                if (r < N) {
                    ahi[rt] = *(const bf16x8*)(a_bf + (size_t)(rblk + rt) * 2048 + (ks * 4 + lg) * 128 + l15 * 8);
                } else {
                    bf16x8 z = {0, 0, 0, 0, 0, 0, 0, 0};
                    ahi[rt] = z;
                }
            }
        }
#pragma unroll
        for (int ct = 0; ct < 8; ++ct) {
            size_t boff = (size_t)(((ct * 4 + ks) * 64 + lane) * 8);
            bf16x8 bhi = *(const bf16x8*)(wt_hi + boff);
            bf16x8 blo = *(const bf16x8*)(wt_lo + boff);
            acc[0][ct] = __builtin_amdgcn_mfma_f32_16x16x32_bf16(ahi[0], bhi, acc[0][ct], 0, 0, 0);
            acc[1][ct] = __builtin_amdgcn_mfma_f32_16x16x32_bf16(ahi[1], bhi, acc[1][ct], 0, 0, 0);
            acc[0][ct] = __builtin_amdgcn_mfma_f32_16x16x32_bf16(ahi[0], blo, acc[0][ct], 0, 0, 0);
            acc[1][ct] = __builtin_amdgcn_mfma_f32_16x16x32_bf16(ahi[1], blo, acc[1][ct], 0, 0, 0);
            if (F32A) {
                acc[0][ct] = __builtin_amdgcn_mfma_f32_16x16x32_bf16(alo[0], bhi, acc[0][ct], 0, 0, 0);
                acc[1][ct] = __builtin_amdgcn_mfma_f32_16x16x32_bf16(alo[1], bhi, acc[1][ct], 0, 0, 0);
            }
        }
    }

#pragma unroll
    for (int rt = 0; rt < 2; ++rt) {
#pragma unroll
        for (int reg = 0; reg < 4; ++reg) {
            int row = rowBase + rt * 16 + lg * 4 + reg;
            if (row >= N) continue;
            if (MODE == 0) {
                int r16 = lg * 4 + reg;
#pragma unroll
                for (int ct = 0; ct < 8; ++ct) {
                    int colc = ct * 16 + l15;
                    float v = acc[rt][ct][reg] + bias[colc];
                    v = v > 0.f ? v : expf(v) - 1.f;
                    out0[(size_t)(rblk + rt) * 2048 + (colc >> 3) * 128 + r16 * 8 + (colc & 7)] = f2bf(v);
                }
            } else {
                float dv = dinv[row];
#pragma unroll
                for (int ct = 0; ct < 8; ++ct) {
                    int colc = ct * 16 + l15;
                    out0[(size_t)row * 128 + colc] = f2bf(acc[rt][ct][reg] * dv);
                }
            }
        }
    }
}

// ---------------- K3: scatter (blocks 0..NPARTB-1, atomic-free bases) + gemm1 ----------------
__global__ __launch_bounds__(256) void part_gemm1(const int* __restrict__ erow, const int* __restrict__ ecol,
                                                  const int* __restrict__ brp, const int* __restrict__ basew,
                                                  unsigned int* __restrict__ pairs,
                                                  const float* __restrict__ x,
                                                  const ushort_t* __restrict__ wt_hi,
                                                  const ushort_t* __restrict__ wt_lo,
                                                  const float* __restrict__ lin1_b,
                                                  ushort_t* __restrict__ h) {
    if (blockIdx.x < NPARTB) {
        __shared__ int sbase[NB];
        __shared__ int lcnt[NB];
        const int blk = blockIdx.x, t = threadIdx.x;
        for (int i = t; i < NB; i += 256) {
            sbase[i] = brp[i] + basew[blk * NB + i];
            lcnt[i] = 0;
        }
        __syncthreads();
        const int e0 = blk * PCHUNK;
        const int e1 = min(e0 + PCHUNK, NE);
        for (int e = e0 + t; e < e1; e += 256) {
            int d = ecol[e];
            int b = d / RB;
            int off = atomicAdd(&lcnt[b], 1);
            pairs[sbase[b] + off] = ((unsigned)erow[e] << 8) | (unsigned)(d - b * RB);
        }
    } else {
        gemm_body<true, 0>(blockIdx.x - NPARTB, threadIdx.x, x, nullptr, wt_hi, wt_lo,
                           lin1_b, nullptr, h, NN);
    }
}

// ---------------- fused: bucket_fill (blocks 0..511) + readout0 (blocks 512..2559) ----------------
__global__ __launch_bounds__(256) void fill_readout0(const unsigned int* __restrict__ pairs, const int* __restrict__ brp,
                                                     int* __restrict__ rp, float* __restrict__ dinv,
                                                     int* __restrict__ csrc,
                                                     const ushort_t* __restrict__ h,
                                                     const int* __restrict__ batch,
                                                     const float* __restrict__ invcnt,
                                                     float* __restrict__ reps) {
    if (blockIdx.x < NB) {
        __shared__ int cnt[RB];
        __shared__ int cur[RB];
        __shared__ int sc[256];
        const int b = blockIdx.x, t = threadIdx.x;
        const int nbase = b * RB;
        const int s = brp[b], e = brp[b + 1];
        for (int i = t; i < RB; i += 256) cnt[i] = 0;
        __syncthreads();
        for (int i = s + t; i < e; i += 256) atomicAdd(&cnt[pairs[i] & 255u], 1);
        __syncthreads();
        int v = (t < RB) ? cnt[t] : 0;
        sc[t] = v;
        __syncthreads();
        for (int off = 1; off < 256; off <<= 1) {
            int x = (t >= off) ? sc[t - off] : 0;
            __syncthreads();
            sc[t] += x;
            __syncthreads();
        }
        if (t < RB) {
            int ex = s + sc[t] - v;
            int node = nbase + t;
            if (node < NN) {
                rp[node] = ex;
                dinv[node] = rsqrtf((float)v + 1.0f);
            }
            cur[t] = ex;
        }
        __syncthreads();
        for (int i = s + t; i < e; i += 256) {
            unsigned int p = pairs[i];
            int slot = atomicAdd(&cur[p & 255u], 1);
            csrc[slot] = (int)(p >> 8);
        }
    } else {
        int bb = blockIdx.x - NB;
        int g = bb >> 2;
        int part = bb & 3;
        int lo = 0, hi = NN;
        while (lo < hi) { int m = (lo + hi) >> 1; if (batch[m] < g) lo = m + 1; else hi = m; }
        int s = lo;
        lo = 0; hi = NN;
        while (lo < hi) { int m = (lo + hi) >> 1; if (batch[m] < g + 1) lo = m + 1; else hi = m; }
        int e = lo;

        __shared__ float sh[16][136];
        int ns = (int)(threadIdx.x >> 4);
        int L  = (int)(threadIdx.x & 15);
        int c8 = L << 3;
        float acc[8] = {};
        for (int v = s + part + ns * 4; v < e; v += 64) {
            ushort8_t t = *(const ushort8_t*)(h + (size_t)(v >> 4) * 2048 + L * 128 + (v & 15) * 8);
#pragma unroll
            for (int j = 0; j < 8; ++j) acc[j] += bf2f(t[j]);
        }
#pragma unroll
        for (int j = 0; j < 8; ++j) sh[ns][c8 + j] = acc[j];
        __syncthreads();
        if (threadIdx.x < 128) {
            int c = (int)threadIdx.x;
            float sum = 0.f;
#pragma unroll
            for (int k = 0; k < 16; ++k) sum += sh[k][c];
            unsafeAtomicAdd(&reps[(size_t)g * 128 + c], sum * invcnt[g]);
        }
    }
}

// ---------------- standalone GCN gemm (MODE 1) ----------------
__global__ __launch_bounds__(256) void gemm_gcn(const ushort_t* __restrict__ a_bf,
                                                const ushort_t* __restrict__ wt_hi,
                                                const ushort_t* __restrict__ wt_lo,
                                                const float* __restrict__ dinv,
                                                ushort_t* __restrict__ hwb) {
    gemm_body<false, 1>(blockIdx.x, threadIdx.x, nullptr, a_bf, wt_hi, wt_lo,
                        nullptr, dinv, hwb, NN);
}

// ---------------- gather + fused readout; h written in PERM layout ----------------
__global__ __launch_bounds__(256) void gather_agg(const int* __restrict__ rp,
                                                  const int* __restrict__ csrc,
                                                  const float* __restrict__ dinv,
                                                  const ushort_t* __restrict__ hwb,
                                                  const float* __restrict__ bias,
                                                  const int* __restrict__ batch,
                                                  const float* __restrict__ invcnt,
                                                  float* __restrict__ reps,
                                                  ushort_t* __restrict__ h_out) {
    __shared__ float sh[16][136];
    __shared__ int gid[16];
    const int v0 = blockIdx.x * 16;
    const int ns = (int)(threadIdx.x >> 4);
    int v = v0 + ns;
    int L = (int)(threadIdx.x & 15);
    int c8 = L << 3;
    if (threadIdx.x < 16) {
        int bidx = v0 + (int)threadIdx.x;
        if (bidx > NN - 1) bidx = NN - 1;
        gid[threadIdx.x] = batch[bidx];
    }

    float acc[8] = {};
    if (v < NN) {
        int s = rp[v], e = rp[v + 1];
        int i = s;
        for (; i + 16 <= e; i += 16) {
            int u[16];
#pragma unroll
            for (int k = 0; k < 16; ++k) u[k] = csrc[i + k];
            ushort8_t r[16];
#pragma unroll
            for (int k = 0; k < 16; ++k) r[k] = *(const ushort8_t*)(hwb + (size_t)u[k] * 128 + c8);
#pragma unroll
            for (int k = 0; k < 16; ++k)
#pragma unroll
                for (int j = 0; j < 8; ++j) acc[j] += bf2f(r[k][j]);
        }
        for (; i + 8 <= e; i += 8) {
            int u[8];
#pragma unroll
            for (int k = 0; k < 8; ++k) u[k] = csrc[i + k];
            ushort8_t r[8];
#pragma unroll
            for (int k = 0; k < 8; ++k) r[k] = *(const ushort8_t*)(hwb + (size_t)u[k] * 128 + c8);
#pragma unroll
            for (int k = 0; k < 8; ++k)
#pragma unroll
                for (int j = 0; j < 8; ++j) acc[j] += bf2f(r[k][j]);
        }
        for (; i < e; ++i) {
            int u = csrc[i];
            ushort8_t r0 = *(const ushort8_t*)(hwb + (size_t)u * 128 + c8);
#pragma unroll
            for (int j = 0; j < 8; ++j) acc[j] += bf2f(r0[j]);
        }

        float di = dinv[v];
        ushort8_t sv = *(const ushort8_t*)(hwb + (size_t)v * 128 + c8);
        ushort8_t o;
#pragma unroll
        for (int j = 0; j < 8; ++j) {
            float t = di * (acc[j] + bf2f(sv[j])) + bias[c8 + j];
            t = t > 0.f ? t : expf(t) - 1.f;
            acc[j] = t;
            o[j] = f2bf(t);
        }
        *(ushort8_t*)(h_out + (size_t)blockIdx.x * 2048 + L * 128 + ns * 8) = o;
    } else {
#pragma unroll
        for (int j = 0; j < 8; ++j) acc[j] = 0.f;
    }

#pragma unroll
    for (int j = 0; j < 8; ++j) sh[ns][c8 + j] = acc[j];
    __syncthreads();
    if (threadIdx.x < 128) {
        int c = (int)threadIdx.x;
        int nvalid = NN - v0;
        if (nvalid > 16) nvalid = 16;
        float run = sh[0][c];
        int cg = gid[0];
        for (int k = 1; k < nvalid; ++k) {
            int g2 = gid[k];
            if (g2 != cg) {
                unsafeAtomicAdd(&reps[(size_t)cg * 128 + c], run * invcnt[cg]);
                run = 0.f;
                cg = g2;
            }
            run += sh[k][c];
        }
        unsafeAtomicAdd(&reps[(size_t)cg * 128 + c], run * invcnt[cg]);
    }
}

// ---------------- fused head ----------------
__global__ __launch_bounds__(128) void head_fused(const float* __restrict__ reps,
                                                  const float* __restrict__ wout,
                                                  const float* __restrict__ bout,
                                                  const float* __restrict__ cw,
                                                  const float* __restrict__ cb,
                                                  float* __restrict__ out) {
    __shared__ float rrow[128];
    __shared__ float gg[128];
    __shared__ float lg[10];
    int t = threadIdx.x;
    int g = blockIdx.x;
    rrow[t] = reps[(size_t)g * 128 + t];
    __syncthreads();
    float a = bout[t];
    for (int k = 0; k < 128; ++k) a = fmaf(rrow[k], wout[k * 128 + t], a);
    a = a > 0.f ? a : expf(a) - 1.f;
    gg[t] = a;
    __syncthreads();
    if (t < 10) {
        float s = cb[t];
        for (int k = 0; k < 128; ++k) s = fmaf(gg[k], cw[k * 10 + t], s);
        lg[t] = s;
    }
    __syncthreads();
    if (t == 0) {
        float m = lg[0];
#pragma unroll
        for (int j = 1; j < 10; ++j) m = fmaxf(m, lg[j]);
        float se = 0.f;
#pragma unroll
        for (int j = 0; j < 10; ++j) se += expf(lg[j] - m);
        float L = logf(se);
#pragma unroll
        for (int j = 0; j < 10; ++j) out[(size_t)g * 10 + j] = lg[j] - m - L;
    }
}

extern "C" void kernel_launch(void* const* d_in, const int* in_sizes, int n_in,
                              void* d_out, int out_size, void* d_ws, size_t ws_size,
                              hipStream_t stream) {
    const float* x        = (const float*)d_in[0];
    const float* lin1_w   = (const float*)d_in[1];
    const float* lin1_b   = (const float*)d_in[2];
    const float* gcn_w    = (const float*)d_in[3];
    const float* gcn_b    = (const float*)d_in[4];
    const float* lin_out_w= (const float*)d_in[5];
    const float* lin_out_b= (const float*)d_in[6];
    const float* cls_w    = (const float*)d_in[7];
    const float* cls_b    = (const float*)d_in[8];
    const int*   ei       = (const int*)d_in[9];
    const int*   batch    = (const int*)d_in[10];
    float* out = (float*)d_out;

    const int* erow = ei;
    const int* ecol = ei + NE;

    ushort_t* h     = (ushort_t*)d_ws;                     // NN*128 bf16 (PERM)
    ushort_t* hwb   = h + (size_t)NN * 128;                // NN*128 bf16 (row-major)
    float*    dinv  = (float*)(hwb + (size_t)NN * 128);    // NN
    float*    reps  = dinv + NN;                           // NG*128
    float*    invcnt= reps + (size_t)NG * 128;             // NG
    int*      rp    = (int*)(invcnt + NG);                 // NN+1
    int*      csrc  = rp + NN + 1;                         // NE
    int*      brp   = csrc + NE;                           // NB+1
    int*      bcount= brp + NB + 1;                        // NPARTB*NB
    int*      basew = bcount + NPARTB * NB;                // NPARTB*NB
    ushort_t* wt_hi = (ushort_t*)(basew + NPARTB * NB);    // 4*16384
    ushort_t* wt_lo = wt_hi + 4 * 16384;                   // 4*16384
    unsigned int* pairs = (unsigned int*)(wt_lo + 4 * 16384);  // NE

    hipMemsetAsync(reps, 0, (size_t)NG * 128 * sizeof(float), stream);

    // ---- atomic-free CSR build + weight prep + first GEMM ----
    hist_prepw<<<NPARTB + 32, 256, 0, stream>>>(ecol, bcount, lin1_w, gcn_w, wt_hi, wt_lo);
    scan_bases<<<1, NB, 0, stream>>>(bcount, basew, brp, rp, batch, invcnt);
    part_gemm1<<<NPARTB + GEMM_GRID, 256, 0, stream>>>(erow, ecol, brp, basew, pairs,
                                                       x, wt_hi, wt_lo, lin1_b, h);
    fill_readout0<<<NB + NG * 4, 256, 0, stream>>>(pairs, brp, rp, dinv, csrc,
                                                   h, batch, invcnt, reps);

    for (int i = 0; i < 3; ++i) {
        gemm_gcn<<<GEMM_GRID, 256, 0, stream>>>(h, wt_hi + (size_t)(i + 1) * 16384,
                                                wt_lo + (size_t)(i + 1) * 16384,
                                                dinv, hwb);
        gather_agg<<<(NN + 15) / 16, 256, 0, stream>>>(rp, csrc, dinv, hwb,
                                                       gcn_b + (size_t)i * 128,
                                                       batch, invcnt, reps, h);
    }

    head_fused<<<NG, 128, 0, stream>>>(reps, lin_out_w, lin_out_b, cls_w, cls_b, out);
}